// Round 1
// baseline (6030.836 us; speedup 1.0000x reference)
//
#include <hip/hip_runtime.h>
#include <hip/hip_bf16.h>

#define B_ 16
#define T_ 64
#define E_ 512
#define H_ 512
#define V_ 32000

__device__ __forceinline__ float sigm(float x){ return 1.0f/(1.0f + __expf(-x)); }

// ---------------- embedding gather: one block per token row ----------------
__global__ void k_gather(const int* __restrict__ ids, const float* __restrict__ emb,
                         float* __restrict__ out){
  const int row = blockIdx.x;               // b*T + t
  const int id  = ids[row];
  const float4* s = (const float4*)(emb + (size_t)id * E_);
  float4* d = (float4*)(out + (size_t)row * E_);
  d[threadIdx.x] = s[threadIdx.x];          // 128 thr * 16B = 512 floats
}

// ---------------- f32 GEMM: C[M,N] = A[M,K]@B[K,N] (+bias) -----------------
// BM=BN=128, BK=8, 256 threads, 8x8 per thread. All dims divide exactly here.
__global__ __launch_bounds__(256)
void k_gemm(const float* __restrict__ A, const float* __restrict__ Bm,
            const float* __restrict__ bias, float* __restrict__ C,
            int M, int N, int K){
  __shared__ float As[8][132];   // [k][m], +4 pad
  __shared__ float Bs[8][128];   // [k][n]
  const int tid = threadIdx.x;
  const int bm = blockIdx.y * 128;
  const int bn = blockIdx.x * 128;
  const int tx = tid & 15, ty = tid >> 4;
  float acc[8][8];
  #pragma unroll
  for(int i=0;i<8;i++)
    #pragma unroll
    for(int j=0;j<8;j++) acc[i][j]=0.f;
  const int ia = tid*4;
  const int am = ia >> 3, ak = ia & 7;       // A tile: 128 rows x 8 k
  const int bk = ia >> 7, bn2 = ia & 127;    // B tile: 8 k x 128 cols
  for(int k0=0;k0<K;k0+=8){
    float4 va = *(const float4*)(A  + (size_t)(bm+am)*K + k0 + ak);
    float4 vb = *(const float4*)(Bm + (size_t)(k0+bk)*N + bn + bn2);
    As[ak+0][am]=va.x; As[ak+1][am]=va.y; As[ak+2][am]=va.z; As[ak+3][am]=va.w;
    *(float4*)&Bs[bk][bn2] = vb;
    __syncthreads();
    #pragma unroll
    for(int kk=0;kk<8;kk++){
      float a[8], b[8];
      *(float4*)&a[0] = *(const float4*)&As[kk][ty*8];
      *(float4*)&a[4] = *(const float4*)&As[kk][ty*8+4];
      *(float4*)&b[0] = *(const float4*)&Bs[kk][tx*8];
      *(float4*)&b[4] = *(const float4*)&Bs[kk][tx*8+4];
      #pragma unroll
      for(int i=0;i<8;i++)
        #pragma unroll
        for(int j=0;j<8;j++)
          acc[i][j] = fmaf(a[i], b[j], acc[i][j]);
    }
    __syncthreads();
  }
  #pragma unroll
  for(int i=0;i<8;i++){
    const int row = bm + ty*8 + i;
    #pragma unroll
    for(int j=0;j<8;j+=4){
      const int cc = bn + tx*8 + j;
      float4 v; v.x=acc[i][j]; v.y=acc[i][j+1]; v.z=acc[i][j+2]; v.w=acc[i][j+3];
      if(bias){ v.x+=bias[cc]; v.y+=bias[cc+1]; v.z+=bias[cc+2]; v.w+=bias[cc+3]; }
      *(float4*)(C + (size_t)row*N + cc) = v;
    }
  }
}

// ---------------- one LSTM timestep: z = xw[t] + h@U + b; gates ------------
// HU = hidden units of this layer; block covers UB units x 4 gates, KCH k-chunks.
// threads = UB*4*KCH = 256. grid = HU/UB blocks.
template<int HU, int UB, int KCH>
__global__ __launch_bounds__(256)
void k_lstm_step(const float* __restrict__ xw,    // [B*T][4*HU], row=b*T+t
                 const float* __restrict__ U,     // [HU][4*HU]
                 const float* __restrict__ bias,  // [4*HU]
                 const float* __restrict__ hprev, // [B][HU]
                 const float* __restrict__ cprev, // [B][HU]
                 float* __restrict__ hnext, float* __restrict__ cnext,
                 float* __restrict__ hseq,        // [B*T][HU]
                 int t){
  constexpr int KC = HU / KCH;      // k per chunk (=64 for both configs)
  constexpr int NC = UB * 4;        // z-columns per block
  const int tid  = threadIdx.x;
  const int u    = tid % UB;
  const int g    = (tid / UB) & 3;
  const int kc   = tid / (UB*4);
  const int ubase= blockIdx.x * UB;
  const int col  = g*HU + ubase + u;
  const int N4   = 4*HU;
  const int k0   = kc*KC;
  float acc[B_];
  #pragma unroll
  for(int r=0;r<B_;r++) acc[r]=0.f;
  const float* Up = U + (size_t)k0*N4 + col;
  for(int kk=0; kk<KC; kk+=4){
    float u0 = Up[(size_t)(kk+0)*N4];
    float u1 = Up[(size_t)(kk+1)*N4];
    float u2 = Up[(size_t)(kk+2)*N4];
    float u3 = Up[(size_t)(kk+3)*N4];
    #pragma unroll
    for(int r=0;r<B_;r++){
      float4 h4 = *(const float4*)(hprev + (size_t)r*HU + k0 + kk);
      acc[r] = fmaf(h4.x,u0, fmaf(h4.y,u1, fmaf(h4.z,u2, fmaf(h4.w,u3, acc[r]))));
    }
  }
  __shared__ float zred[KCH][NC][B_];
  #pragma unroll
  for(int r=0;r<B_;r++) zred[kc][g*UB+u][r] = acc[r];
  __syncthreads();
  if(tid < UB*B_){
    const int u2 = tid % UB;
    const int r  = tid / UB;
    float s[4];
    #pragma unroll
    for(int gg=0;gg<4;gg++){
      const int cg = gg*HU + ubase + u2;
      float v = xw[(size_t)(r*T_ + t)*N4 + cg] + bias[cg];
      #pragma unroll
      for(int q=0;q<KCH;q++) v += zred[q][gg*UB+u2][r];
      s[gg]=v;
    }
    const int idx = r*HU + ubase + u2;
    const float co = cprev[idx];
    const float c2 = sigm(s[1])*co + sigm(s[0])*tanhf(s[2]);
    const float h2 = sigm(s[3])*tanhf(c2);
    cnext[idx]=c2; hnext[idx]=h2;
    hseq[(size_t)(r*T_ + t)*HU + ubase + u2] = h2;
  }
}

// ---------------- init states -------------------------------------------
__global__ void k_init1(const float* __restrict__ init_state,
                        float* h0, float* c0, float* h1, float* c1){
  int i = blockIdx.x*blockDim.x + threadIdx.x;  // 0..8191
  if(i >= B_*H_) return;
  float v0 = init_state[i];
  float v1 = init_state[B_*H_ + i];
  h0[i]=v0; c0[i]=v0; h1[i]=v1; c1[i]=v1;
}

__global__ void k_init2(const float* __restrict__ init_state,
                        const float* __restrict__ h1f0, const float* __restrict__ c1f0,
                        const float* __restrict__ h1f1, const float* __restrict__ c1f1,
                        float* h20, float* c20, float* h21, float* c21){
  const int l = blockIdx.y;
  const int i = blockIdx.x*blockDim.x + threadIdx.x;  // 0..16383 over [B][2H]
  if(i >= B_*2*H_) return;
  const int b = i >> 10, j = i & 1023;
  const float* hf = l ? h1f1 : h1f0;
  const float* cf = l ? c1f1 : c1f0;
  float* ho = l ? h21 : h20;
  float* co = l ? c21 : c20;
  float vh, vc;
  if(j < H_){ vh = init_state[(size_t)l*B_*H_ + b*H_ + j]; vc = vh; }
  else      { vh = hf[b*H_ + j - H_]; vc = cf[b*H_ + j - H_]; }
  ho[i]=vh; co[i]=vc;
}

extern "C" void kernel_launch(void* const* d_in, const int* in_sizes, int n_in,
                              void* d_out, int out_size, void* d_ws, size_t ws_size,
                              hipStream_t stream){
  const int*   ids1 = (const int*)d_in[0];
  const int*   ids2 = (const int*)d_in[1];
  const float* init = (const float*)d_in[2];
  const float* emb  = (const float*)d_in[3];
  const float* W1_0 = (const float*)d_in[4];
  const float* U1_0 = (const float*)d_in[5];
  const float* b1_0 = (const float*)d_in[6];
  const float* W1_1 = (const float*)d_in[7];
  const float* U1_1 = (const float*)d_in[8];
  const float* b1_1 = (const float*)d_in[9];
  const float* W2_0 = (const float*)d_in[10];
  const float* U2_0 = (const float*)d_in[11];
  const float* b2_0 = (const float*)d_in[12];
  const float* W2_1 = (const float*)d_in[13];
  const float* U2_1 = (const float*)d_in[14];
  const float* b2_1 = (const float*)d_in[15];
  const float* Wp1  = (const float*)d_in[16];
  const float* bp1  = (const float*)d_in[17];
  const float* Wp2  = (const float*)d_in[18];
  const float* bp2  = (const float*)d_in[19];
  float* out1 = (float*)d_out;
  float* out2 = out1 + (size_t)B_*T_*V_;

  // workspace layout (floats) — ~27 MB total
  float* ws    = (float*)d_ws;
  float* ebuf  = ws;                    // 1024 x 512
  float* xwbuf = ebuf  + 524288;        // up to 1024 x 4096
  float* seqA  = xwbuf + 4194304;       // up to 1024 x 1024
  float* seqB  = seqA  + 1048576;       // up to 1024 x 1024
  float* h1s   = seqB  + 1048576;       // RNN1 h: [layer][pingpong][16*512]
  float* c1s   = h1s + 4*8192;
  float* h2s   = c1s + 4*8192;          // RNN2 h: [layer][pingpong][16*1024]
  float* c2s   = h2s + 4*16384;

  auto h1 = [&](int l,int p){ return h1s + (size_t)((l<<1)|p)*8192; };
  auto c1 = [&](int l,int p){ return c1s + (size_t)((l<<1)|p)*8192; };
  auto h2 = [&](int l,int p){ return h2s + (size_t)((l<<1)|p)*16384; };
  auto c2 = [&](int l,int p){ return c2s + (size_t)((l<<1)|p)*16384; };

  // ---- RNN1 ----
  k_init1<<<dim3(32),dim3(256),0,stream>>>(init, h1(0,0), c1(0,0), h1(1,0), c1(1,0));
  k_gather<<<dim3(B_*T_),dim3(128),0,stream>>>(ids1, emb, ebuf);
  // xw1_0 = e1 @ W1_0 : [1024,512]@[512,2048]
  k_gemm<<<dim3(16,8),dim3(256),0,stream>>>(ebuf, W1_0, nullptr, xwbuf, 1024, 2048, 512);
  for(int t=0;t<T_;t++)
    k_lstm_step<512,8,8><<<dim3(64),dim3(256),0,stream>>>(
        xwbuf, U1_0, b1_0, h1(0,t&1), c1(0,t&1), h1(0,(t+1)&1), c1(0,(t+1)&1), seqA, t);
  // xw1_1 = h0seq @ W1_1 : [1024,512]@[512,2048]
  k_gemm<<<dim3(16,8),dim3(256),0,stream>>>(seqA, W1_1, nullptr, xwbuf, 1024, 2048, 512);
  for(int t=0;t<T_;t++)
    k_lstm_step<512,8,8><<<dim3(64),dim3(256),0,stream>>>(
        xwbuf, U1_1, b1_1, h1(1,t&1), c1(1,t&1), h1(1,(t+1)&1), c1(1,(t+1)&1), seqB, t);
  // logits1 = out1 @ Wp1 + bp1 : [1024,512]@[512,32000]
  k_gemm<<<dim3(250,8),dim3(256),0,stream>>>(seqB, Wp1, bp1, out1, 1024, V_, 512);

  // ---- RNN2 ---- (init h/c = concat(init_state, rnn1 final))
  k_init2<<<dim3(64,2),dim3(256),0,stream>>>(init, h1(0,0), c1(0,0), h1(1,0), c1(1,0),
                                             h2(0,0), c2(0,0), h2(1,0), c2(1,0));
  k_gather<<<dim3(B_*T_),dim3(128),0,stream>>>(ids2, emb, ebuf);
  // xw2_0 = e2 @ W2_0 : [1024,512]@[512,4096]
  k_gemm<<<dim3(32,8),dim3(256),0,stream>>>(ebuf, W2_0, nullptr, xwbuf, 1024, 4096, 512);
  for(int t=0;t<T_;t++)
    k_lstm_step<1024,4,16><<<dim3(256),dim3(256),0,stream>>>(
        xwbuf, U2_0, b2_0, h2(0,t&1), c2(0,t&1), h2(0,(t+1)&1), c2(0,(t+1)&1), seqA, t);
  // xw2_1 = h0seq2 @ W2_1 : [1024,1024]@[1024,4096]
  k_gemm<<<dim3(32,8),dim3(256),0,stream>>>(seqA, W2_1, nullptr, xwbuf, 1024, 4096, 1024);
  for(int t=0;t<T_;t++)
    k_lstm_step<1024,4,16><<<dim3(256),dim3(256),0,stream>>>(
        xwbuf, U2_1, b2_1, h2(1,t&1), c2(1,t&1), h2(1,(t+1)&1), c2(1,(t+1)&1), seqB, t);
  // logits2 = out2 @ Wp2 + bp2 : [1024,1024]@[1024,32000]
  k_gemm<<<dim3(250,8),dim3(256),0,stream>>>(seqB, Wp2, bp2, out2, 1024, V_, 1024);
}

// Round 2
// 3548.086 us; speedup vs baseline: 1.6997x; 1.6997x over previous
//
#include <hip/hip_runtime.h>
#include <hip/hip_bf16.h>

#define B_ 16
#define T_ 64
#define E_ 512
#define H_ 512
#define V_ 32000

typedef __attribute__((ext_vector_type(4))) float f32x4;
typedef __attribute__((ext_vector_type(8))) short s16x8;

__device__ __forceinline__ float sigm(float x){ return 1.0f/(1.0f + __expf(-x)); }

__device__ __forceinline__ unsigned short f2bf(float x){
  unsigned int u = __float_as_uint(x);
  unsigned int r = (u + 0x7FFFu + ((u>>16)&1u)) >> 16;
  return (unsigned short)r;
}

// ------------- embedding gather -> bf16 [1024][512] ------------------------
__global__ void k_gather(const int* __restrict__ ids, const float* __restrict__ emb,
                         unsigned short* __restrict__ out){
  const int row = blockIdx.x;
  const int id  = ids[row];
  float4 v = *(const float4*)(emb + (size_t)id*E_ + threadIdx.x*4);
  ushort4 o;
  o.x = f2bf(v.x); o.y = f2bf(v.y); o.z = f2bf(v.z); o.w = f2bf(v.w);
  *(ushort4*)(out + (size_t)row*E_ + threadIdx.x*4) = o;
}

// ------------- transpose+convert(+permute): f32 [K][N] -> bf16 [N][K] ------
// permuted row p(n) = (n%Hp)*4 + n/Hp when Hp>0
__global__ __launch_bounds__(256)
void k_tcvt(const float* __restrict__ in, unsigned short* __restrict__ out,
            int K, int N, int Hp){
  __shared__ float tile[32][33];
  const int n0 = blockIdx.x*32, k0 = blockIdx.y*32;
  const int x = threadIdx.x & 31, y = threadIdx.x >> 5;   // y: 0..7
  #pragma unroll
  for(int i=0;i<4;i++){
    int k = y + i*8;
    tile[k][x] = in[(size_t)(k0+k)*N + n0 + x];
  }
  __syncthreads();
  #pragma unroll
  for(int i=0;i<4;i++){
    int nl = y + i*8;
    int n  = n0 + nl;
    int p  = Hp ? ((n % Hp)*4 + n / Hp) : n;
    out[(size_t)p*K + k0 + x] = f2bf(tile[x][nl]);
  }
}

// ------------- bias permute: bpk[p] = b[(p&3)*H + (p>>2)] -------------------
__global__ void k_bpack(const float* __restrict__ b, float* __restrict__ out, int H, int N){
  int p = blockIdx.x*256 + threadIdx.x;
  if(p < N) out[p] = b[(p&3)*H + (p>>2)];
}

// ------------- init states --------------------------------------------------
__global__ void k_init1(const float* __restrict__ init_state,
                        unsigned short* h0, float* c0, unsigned short* h1, float* c1){
  int i = blockIdx.x*256 + threadIdx.x;      // 0..8191  [16][512]
  if(i >= B_*H_) return;
  float v0 = init_state[i];
  float v1 = init_state[B_*H_ + i];
  h0[i] = f2bf(v0); c0[i] = v0;
  h1[i] = f2bf(v1); c1[i] = v1;
}

__global__ void k_init2(const float* __restrict__ init_state,
                        const unsigned short* __restrict__ h1f0, const float* __restrict__ c1f0,
                        const unsigned short* __restrict__ h1f1, const float* __restrict__ c1f1,
                        unsigned short* h20, float* c20, unsigned short* h21, float* c21){
  const int l = blockIdx.y;
  int i = blockIdx.x*256 + threadIdx.x;      // 0..16383 over [16][1024]
  if(i >= B_*2*H_) return;
  const int r = i >> 10, j = i & 1023;
  const unsigned short* hf = l ? h1f1 : h1f0;
  const float* cf = l ? c1f1 : c1f0;
  unsigned short* ho = l ? h21 : h20;
  float* co = l ? c21 : c20;
  if(j < H_){
    float v = init_state[(size_t)l*B_*H_ + r*H_ + j];
    ho[i] = f2bf(v); co[i] = v;
  } else {
    ho[i] = hf[r*H_ + j - H_];
    co[i] = cf[r*H_ + j - H_];
  }
}

// ------------- MFMA GEMM: C[M][N] = A[M][K](bf16) @ B + bias ---------------
// BF32=0: Bsrc = bf16 [N][K] (pre-transposed), staged via global_load_lds
// BF32=1: Bsrc = f32  [K][N], converted+transposed into LDS in-kernel
template<int BF32>
__global__ __launch_bounds__(256)
void k_mm(const unsigned short* __restrict__ A, const void* __restrict__ Bsrc,
          const float* __restrict__ bias, float* __restrict__ C,
          int M, int N, int K){
  __shared__ __align__(16) unsigned short As[128*64];
  __shared__ __align__(16) unsigned short Bs[128*64];
  const int tid = threadIdx.x;
  const int lane = tid & 63, w = tid >> 6;
  const int wm = (w>>1)*64, wn = (w&1)*64;
  const int bm = blockIdx.y*128, bn = blockIdx.x*128;
  const int l15 = lane & 15, kg = lane >> 4;
  f32x4 acc[4][4] = {};

  for(int k0=0; k0<K; k0+=64){
    __syncthreads();
    // stage A tile [128][64] bf16, source pre-swizzled so swizzled reads work
    #pragma unroll
    for(int ch=0; ch<4; ch++){
      int off = ch*4096 + tid*16;            // byte offset in tile
      int row = off >> 7;
      int s   = ((off >> 4) & 7) ^ (row & 7);
      __builtin_amdgcn_global_load_lds(
        (const __attribute__((address_space(1))) unsigned int*)(A + (size_t)(bm+row)*K + k0 + s*8),
        (__attribute__((address_space(3))) unsigned int*)((char*)As + off), 16, 0, 0);
    }
    if(BF32){
      const float* Bf = (const float*)Bsrc;
      #pragma unroll
      for(int i=0;i<8;i++){
        int kl = (tid>>5) + i*8;             // 0..63
        int nl = (tid&31)*4;                 // 0..124
        float4 v = *(const float4*)(Bf + (size_t)(k0+kl)*N + bn + nl);
        int slot = kl >> 3, kb = kl & 7;
        float vv[4] = {v.x, v.y, v.z, v.w};
        #pragma unroll
        for(int jj=0;jj<4;jj++){
          int n = nl + jj;
          Bs[n*64 + ((slot ^ (n&7))*8) + kb] = f2bf(vv[jj]);
        }
      }
    } else {
      const unsigned short* Bt = (const unsigned short*)Bsrc;
      #pragma unroll
      for(int ch=0; ch<4; ch++){
        int off = ch*4096 + tid*16;
        int row = off >> 7;
        int s   = ((off >> 4) & 7) ^ (row & 7);
        __builtin_amdgcn_global_load_lds(
          (const __attribute__((address_space(1))) unsigned int*)(Bt + (size_t)(bn+row)*K + k0 + s*8),
          (__attribute__((address_space(3))) unsigned int*)((char*)Bs + off), 16, 0, 0);
      }
    }
    __syncthreads();

    #pragma unroll
    for(int q=0;q<2;q++){
      s16x8 af[4], bf[4];
      #pragma unroll
      for(int mt=0;mt<4;mt++){
        int row = wm + mt*16 + l15;
        int s = (q*4 + kg) ^ (row & 7);
        af[mt] = *(const s16x8*)(As + row*64 + s*8);
      }
      #pragma unroll
      for(int nt=0;nt<4;nt++){
        int row = wn + nt*16 + l15;
        int s = (q*4 + kg) ^ (row & 7);
        bf[nt] = *(const s16x8*)(Bs + row*64 + s*8);
      }
      #pragma unroll
      for(int mt=0;mt<4;mt++)
        #pragma unroll
        for(int nt=0;nt<4;nt++)
          acc[mt][nt] = __builtin_amdgcn_mfma_f32_16x16x32_bf16(af[mt], bf[nt], acc[mt][nt], 0, 0, 0);
    }
  }
  // epilogue: C/D layout col=lane&15, row=(lane>>4)*4+e  [m89 verified]
  #pragma unroll
  for(int mt=0;mt<4;mt++){
    #pragma unroll
    for(int nt=0;nt<4;nt++){
      int col = bn + wn + nt*16 + l15;
      float bv = bias ? bias[col] : 0.f;
      #pragma unroll
      for(int e=0;e<4;e++){
        int row = bm + wm + mt*16 + kg*4 + e;
        C[(size_t)row*N + col] = acc[mt][nt][e] + bv;
      }
    }
  }
}

// ------------- LSTM step: z[16][N] = h@Ut^T; fused gates -------------------
// Ut: bf16 [N][K] packed (p = u*4+g); xw: f32 [1024][N] packed; bpk: f32 [N]
__global__ __launch_bounds__(256)
void k_step(const unsigned short* __restrict__ Ut,
            const float* __restrict__ xw,
            const float* __restrict__ bpk,
            const unsigned short* __restrict__ hin,  // [16][K]
            const float* __restrict__ cin,           // [16][HU]
            unsigned short* __restrict__ hout,
            float* __restrict__ cout,
            unsigned short* __restrict__ hseq,       // [1024][HU]
            int K, int HU, int N, int t){
  const int tid = threadIdx.x;
  const int lane = tid & 63, w = tid >> 6;
  const int c0 = blockIdx.x*128 + w*32;
  const int l15 = lane & 15, kg = lane >> 4;
  f32x4 acc0 = {}, acc1 = {};
  const unsigned short* ap  = hin + (size_t)l15*K + kg*8;
  const unsigned short* b0p = Ut + (size_t)(c0 + l15)*K + kg*8;
  const unsigned short* b1p = Ut + (size_t)(c0 + 16 + l15)*K + kg*8;
  #pragma unroll 2
  for(int k0=0; k0<K; k0+=32){
    s16x8 a  = *(const s16x8*)(ap  + k0);
    s16x8 b0 = *(const s16x8*)(b0p + k0);
    s16x8 b1 = *(const s16x8*)(b1p + k0);
    acc0 = __builtin_amdgcn_mfma_f32_16x16x32_bf16(a, b0, acc0, 0, 0, 0);
    acc1 = __builtin_amdgcn_mfma_f32_16x16x32_bf16(a, b1, acc1, 0, 0, 0);
  }
  __shared__ float z[4][16][33];
  #pragma unroll
  for(int e=0;e<4;e++){
    int r = kg*4 + e;
    z[w][r][l15]      = acc0[e];
    z[w][r][16 + l15] = acc1[e];
  }
  __syncthreads();
  #pragma unroll
  for(int i=0;i<2;i++){
    int item = tid + i*256;            // 512 items = 16 rows x 32 units
    int r = item >> 5, uu = item & 31;
    int pw = uu >> 3, pc = (uu & 7)*4;
    float zi = z[pw][r][pc],   zf = z[pw][r][pc+1];
    float zg = z[pw][r][pc+2], zo = z[pw][r][pc+3];
    int pg = blockIdx.x*128 + uu*4;
    float4 xv = *(const float4*)(xw + (size_t)(r*T_ + t)*N + pg);
    float4 bv = *(const float4*)(bpk + pg);
    float si = zi + xv.x + bv.x;
    float sf = zf + xv.y + bv.y;
    float sg = zg + xv.z + bv.z;
    float so = zo + xv.w + bv.w;
    int hu = blockIdx.x*32 + uu;
    float c2 = sigm(sf)*cin[r*HU + hu] + sigm(si)*tanhf(sg);
    float h2 = sigm(so)*tanhf(c2);
    cout[r*HU + hu] = c2;
    unsigned short hb = f2bf(h2);
    hout[r*HU + hu] = hb;
    hseq[(size_t)(r*T_ + t)*HU + hu] = hb;
  }
}

// ---------------------------------------------------------------------------
extern "C" void kernel_launch(void* const* d_in, const int* in_sizes, int n_in,
                              void* d_out, int out_size, void* d_ws, size_t ws_size,
                              hipStream_t stream){
  const int*   ids1 = (const int*)d_in[0];
  const int*   ids2 = (const int*)d_in[1];
  const float* init = (const float*)d_in[2];
  const float* emb  = (const float*)d_in[3];
  const float* W1_0 = (const float*)d_in[4];
  const float* U1_0 = (const float*)d_in[5];
  const float* b1_0 = (const float*)d_in[6];
  const float* W1_1 = (const float*)d_in[7];
  const float* U1_1 = (const float*)d_in[8];
  const float* b1_1 = (const float*)d_in[9];
  const float* W2_0 = (const float*)d_in[10];
  const float* U2_0 = (const float*)d_in[11];
  const float* b2_0 = (const float*)d_in[12];
  const float* W2_1 = (const float*)d_in[13];
  const float* U2_1 = (const float*)d_in[14];
  const float* b2_1 = (const float*)d_in[15];
  const float* Wp1  = (const float*)d_in[16];
  const float* bp1  = (const float*)d_in[17];
  const float* Wp2  = (const float*)d_in[18];
  const float* bp2  = (const float*)d_in[19];
  float* out1 = (float*)d_out;
  float* out2 = out1 + (size_t)B_*T_*V_;

  char* base = (char*)d_ws;
  float*          xw    = (float*)(base);                         // 16 MB [1024][4096]
  unsigned short* seqA  = (unsigned short*)(base + (16u<<20));    // 2 MB  [1024][1024]
  unsigned short* seqB  = (unsigned short*)(base + (18u<<20));    // 2 MB
  unsigned short* ebuf  = (unsigned short*)(base + (20u<<20));    // 1 MB  [1024][512]
  unsigned short* utbuf = (unsigned short*)(base + (21u<<20));    // 8 MB
  unsigned short* wtbuf = (unsigned short*)(base + (29u<<20));    // 8 MB
  float*          bpk   = (float*)(base + (37u<<20));             // 16 KB
  char* st = base + (38u<<20);
  // RNN1: h bf16 [16][512]=16KB x4, c f32 32KB x4; RNN2: h 32KB x4, c 64KB x4
  auto h1 = [&](int l,int p){ return (unsigned short*)(st + (size_t)(l*2+p)*16384); };
  auto c1 = [&](int l,int p){ return (float*)(st + 65536 + (size_t)(l*2+p)*32768); };
  auto h2 = [&](int l,int p){ return (unsigned short*)(st + 196608 + (size_t)(l*2+p)*32768); };
  auto c2 = [&](int l,int p){ return (float*)(st + 327680 + (size_t)(l*2+p)*65536); };

  // ================= RNN1 =================
  k_init1<<<dim3(32), dim3(256), 0, stream>>>(init, h1(0,0), c1(0,0), h1(1,0), c1(1,0));
  k_gather<<<dim3(B_*T_), dim3(128), 0, stream>>>(ids1, emb, ebuf);
  // layer 0
  k_tcvt<<<dim3(2048/32, 512/32), dim3(256), 0, stream>>>(U1_0, utbuf, 512, 2048, 512);
  k_tcvt<<<dim3(2048/32, 512/32), dim3(256), 0, stream>>>(W1_0, wtbuf, 512, 2048, 512);
  k_bpack<<<dim3(8), dim3(256), 0, stream>>>(b1_0, bpk, 512, 2048);
  k_mm<0><<<dim3(16, 8), dim3(256), 0, stream>>>(ebuf, wtbuf, nullptr, xw, 1024, 2048, 512);
  for(int t=0;t<T_;t++)
    k_step<<<dim3(16), dim3(256), 0, stream>>>(utbuf, xw, bpk,
        h1(0,t&1), c1(0,t&1), h1(0,(t+1)&1), c1(0,(t+1)&1), seqA, 512, 512, 2048, t);
  // layer 1
  k_tcvt<<<dim3(2048/32, 512/32), dim3(256), 0, stream>>>(U1_1, utbuf, 512, 2048, 512);
  k_tcvt<<<dim3(2048/32, 512/32), dim3(256), 0, stream>>>(W1_1, wtbuf, 512, 2048, 512);
  k_bpack<<<dim3(8), dim3(256), 0, stream>>>(b1_1, bpk, 512, 2048);
  k_mm<0><<<dim3(16, 8), dim3(256), 0, stream>>>(seqA, wtbuf, nullptr, xw, 1024, 2048, 512);
  for(int t=0;t<T_;t++)
    k_step<<<dim3(16), dim3(256), 0, stream>>>(utbuf, xw, bpk,
        h1(1,t&1), c1(1,t&1), h1(1,(t+1)&1), c1(1,(t+1)&1), seqB, 512, 512, 2048, t);
  // projection 1 (in-kernel f32->bf16 B staging)
  k_mm<1><<<dim3(250, 8), dim3(256), 0, stream>>>(seqB, Wp1, bp1, out1, 1024, V_, 512);

  // ================= RNN2 =================
  k_init2<<<dim3(64, 2), dim3(256), 0, stream>>>(init, h1(0,0), c1(0,0), h1(1,0), c1(1,0),
                                                 h2(0,0), c2(0,0), h2(1,0), c2(1,0));
  k_gather<<<dim3(B_*T_), dim3(128), 0, stream>>>(ids2, emb, ebuf);
  // layer 0 (input E=512, state 1024)
  k_tcvt<<<dim3(4096/32, 1024/32), dim3(256), 0, stream>>>(U2_0, utbuf, 1024, 4096, 1024);
  k_tcvt<<<dim3(4096/32, 512/32),  dim3(256), 0, stream>>>(W2_0, wtbuf, 512, 4096, 1024);
  k_bpack<<<dim3(16), dim3(256), 0, stream>>>(b2_0, bpk, 1024, 4096);
  k_mm<0><<<dim3(32, 8), dim3(256), 0, stream>>>(ebuf, wtbuf, nullptr, xw, 1024, 4096, 512);
  for(int t=0;t<T_;t++)
    k_step<<<dim3(32), dim3(256), 0, stream>>>(utbuf, xw, bpk,
        h2(0,t&1), c2(0,t&1), h2(0,(t+1)&1), c2(0,(t+1)&1), seqA, 1024, 1024, 4096, t);
  // layer 1
  k_tcvt<<<dim3(4096/32, 1024/32), dim3(256), 0, stream>>>(U2_1, utbuf, 1024, 4096, 1024);
  k_tcvt<<<dim3(4096/32, 1024/32), dim3(256), 0, stream>>>(W2_1, wtbuf, 1024, 4096, 1024);
  k_bpack<<<dim3(16), dim3(256), 0, stream>>>(b2_1, bpk, 1024, 4096);
  k_mm<0><<<dim3(32, 8), dim3(256), 0, stream>>>(seqA, wtbuf, nullptr, xw, 1024, 4096, 1024);
  for(int t=0;t<T_;t++)
    k_step<<<dim3(32), dim3(256), 0, stream>>>(utbuf, xw, bpk,
        h2(1,t&1), c2(1,t&1), h2(1,(t+1)&1), c2(1,(t+1)&1), seqB, 1024, 1024, 4096, t);
  // projection 2
  k_mm<1><<<dim3(250, 8), dim3(256), 0, stream>>>(seqB, Wp2, bp2, out2, 1024, V_, 1024);
}

// Round 3
// 3376.649 us; speedup vs baseline: 1.7860x; 1.0508x over previous
//
#include <hip/hip_runtime.h>
#include <hip/hip_bf16.h>

#define B_ 16
#define T_ 64
#define E_ 512
#define H_ 512
#define V_ 32000

typedef __attribute__((ext_vector_type(4))) float f32x4;
typedef __attribute__((ext_vector_type(8))) short s16x8;

__device__ __forceinline__ float sigm(float x){ return 1.0f/(1.0f + __expf(-x)); }

__device__ __forceinline__ unsigned short f2bf(float x){
  unsigned int u = __float_as_uint(x);
  unsigned int r = (u + 0x7FFFu + ((u>>16)&1u)) >> 16;
  return (unsigned short)r;
}

// ---------------- device-scope grid barrier (generation based) -------------
__device__ __forceinline__ void gbar(unsigned* bar, unsigned nblk){
  __syncthreads();
  if(threadIdx.x == 0){
    __threadfence();
    unsigned g = __hip_atomic_load(bar+1, __ATOMIC_RELAXED, __HIP_MEMORY_SCOPE_AGENT);
    unsigned a = __hip_atomic_fetch_add(bar, 1u, __ATOMIC_ACQ_REL, __HIP_MEMORY_SCOPE_AGENT);
    if(a == nblk-1u){
      __hip_atomic_store(bar, 0u, __ATOMIC_RELAXED, __HIP_MEMORY_SCOPE_AGENT);
      __hip_atomic_store(bar+1, g+1u, __ATOMIC_RELEASE, __HIP_MEMORY_SCOPE_AGENT);
    }else{
      while(__hip_atomic_load(bar+1, __ATOMIC_ACQUIRE, __HIP_MEMORY_SCOPE_AGENT) == g)
        __builtin_amdgcn_s_sleep(2);
    }
  }
  __syncthreads();
}

__global__ void k_barinit(unsigned* bar){ bar[0] = 0u; bar[1] = 0u; }

// ------------- embedding gather -> bf16 [1024][512] ------------------------
__global__ void k_gather(const int* __restrict__ ids, const float* __restrict__ emb,
                         unsigned short* __restrict__ out){
  const int row = blockIdx.x;
  const int id  = ids[row];
  float4 v = *(const float4*)(emb + (size_t)id*E_ + threadIdx.x*4);
  ushort4 o;
  o.x = f2bf(v.x); o.y = f2bf(v.y); o.z = f2bf(v.z); o.w = f2bf(v.w);
  *(ushort4*)(out + (size_t)row*E_ + threadIdx.x*4) = o;
}

// ------------- transpose+convert(+permute): f32 [Ksrc][N] -> bf16 [N][Kfull]
// row p(n) = (n%Hp)*4 + n/Hp when Hp>0; dest col offset koff.
__global__ __launch_bounds__(256)
void k_tcvt(const float* __restrict__ in, unsigned short* __restrict__ out,
            int N, int Hp, int Kfull, int koff){
  __shared__ float tile[32][33];
  const int n0 = blockIdx.x*32, k0 = blockIdx.y*32;
  const int x = threadIdx.x & 31, y = threadIdx.x >> 5;
  #pragma unroll
  for(int i=0;i<4;i++){
    int k = y + i*8;
    tile[k][x] = in[(size_t)(k0+k)*N + n0 + x];
  }
  __syncthreads();
  #pragma unroll
  for(int i=0;i<4;i++){
    int nl = y + i*8;
    int n  = n0 + nl;
    int p  = Hp ? ((n % Hp)*4 + n / Hp) : n;
    out[(size_t)p*Kfull + koff + k0 + x] = f2bf(tile[x][nl]);
  }
}

// ------------- bias permute: bpk[p] = b[(p&3)*H + (p>>2)] -------------------
__global__ void k_bpack(const float* __restrict__ b, float* __restrict__ out, int H, int N){
  int p = blockIdx.x*256 + threadIdx.x;
  if(p < N) out[p] = b[(p&3)*H + (p>>2)];
}

// ------------- init states --------------------------------------------------
__global__ void k_init1(const float* __restrict__ init_state,
                        unsigned short* h0i, float* c0i, unsigned short* h1i, float* c1i){
  int i = blockIdx.x*256 + threadIdx.x;      // [16][512]
  if(i >= B_*H_) return;
  float v0 = init_state[i];
  float v1 = init_state[B_*H_ + i];
  h0i[i] = f2bf(v0); c0i[i] = v0;
  h1i[i] = f2bf(v1); c1i[i] = v1;
}

__global__ void k_init2(const float* __restrict__ init_state,
                        const unsigned short* __restrict__ h0seq1,
                        const unsigned short* __restrict__ h1seq1,
                        const float* __restrict__ c0f1, const float* __restrict__ c1f1,
                        unsigned short* h20i, unsigned short* h21i,
                        float* c20i, float* c21i){
  const int l = blockIdx.y;
  int i = blockIdx.x*256 + threadIdx.x;      // [16][1024]
  if(i >= B_*2*H_) return;
  const int r = i >> 10, j = i & 1023;
  unsigned short* ho = l ? h21i : h20i;
  float* co = l ? c21i : c20i;
  if(j < H_){
    float v = init_state[(size_t)l*B_*H_ + r*H_ + j];
    ho[i] = f2bf(v); co[i] = v;
  } else {
    const unsigned short* hs = l ? h1seq1 : h0seq1;
    const float* cf = l ? c1f1 : c0f1;
    ho[i] = hs[(size_t)(r*T_ + (T_-1))*H_ + (j - H_)];
    co[i] = cf[r*H_ + (j - H_)];
  }
}

// ------------- MFMA GEMM: C[M][N] = A[M][K](bf16) @ B + bias ---------------
template<int BF32>
__global__ __launch_bounds__(256)
void k_mm(const unsigned short* __restrict__ A, const void* __restrict__ Bsrc,
          const float* __restrict__ bias, float* __restrict__ C,
          int M, int N, int K){
  __shared__ __align__(16) unsigned short As[128*64];
  __shared__ __align__(16) unsigned short Bs[128*64];
  const int tid = threadIdx.x;
  const int lane = tid & 63, w = tid >> 6;
  const int wm = (w>>1)*64, wn = (w&1)*64;
  const int bm = blockIdx.y*128, bn = blockIdx.x*128;
  const int l15 = lane & 15, kg = lane >> 4;
  f32x4 acc[4][4] = {};

  for(int k0=0; k0<K; k0+=64){
    __syncthreads();
    #pragma unroll
    for(int ch=0; ch<4; ch++){
      int off = ch*4096 + tid*16;
      int row = off >> 7;
      int s   = ((off >> 4) & 7) ^ (row & 7);
      __builtin_amdgcn_global_load_lds(
        (const __attribute__((address_space(1))) unsigned int*)(A + (size_t)(bm+row)*K + k0 + s*8),
        (__attribute__((address_space(3))) unsigned int*)((char*)As + off), 16, 0, 0);
    }
    if(BF32){
      const float* Bf = (const float*)Bsrc;
      #pragma unroll
      for(int i=0;i<8;i++){
        int kl = (tid>>5) + i*8;
        int nl = (tid&31)*4;
        float4 v = *(const float4*)(Bf + (size_t)(k0+kl)*N + bn + nl);
        int slot = kl >> 3, kb = kl & 7;
        float vv[4] = {v.x, v.y, v.z, v.w};
        #pragma unroll
        for(int jj=0;jj<4;jj++){
          int n = nl + jj;
          Bs[n*64 + ((slot ^ (n&7))*8) + kb] = f2bf(vv[jj]);
        }
      }
    } else {
      const unsigned short* Bt = (const unsigned short*)Bsrc;
      #pragma unroll
      for(int ch=0; ch<4; ch++){
        int off = ch*4096 + tid*16;
        int row = off >> 7;
        int s   = ((off >> 4) & 7) ^ (row & 7);
        __builtin_amdgcn_global_load_lds(
          (const __attribute__((address_space(1))) unsigned int*)(Bt + (size_t)(bn+row)*K + k0 + s*8),
          (__attribute__((address_space(3))) unsigned int*)((char*)Bs + off), 16, 0, 0);
      }
    }
    __syncthreads();

    #pragma unroll
    for(int q=0;q<2;q++){
      s16x8 af[4], bf[4];
      #pragma unroll
      for(int mt=0;mt<4;mt++){
        int row = wm + mt*16 + l15;
        int s = (q*4 + kg) ^ (row & 7);
        af[mt] = *(const s16x8*)(As + row*64 + s*8);
      }
      #pragma unroll
      for(int nt=0;nt<4;nt++){
        int row = wn + nt*16 + l15;
        int s = (q*4 + kg) ^ (row & 7);
        bf[nt] = *(const s16x8*)(Bs + row*64 + s*8);
      }
      #pragma unroll
      for(int mt=0;mt<4;mt++)
        #pragma unroll
        for(int nt=0;nt<4;nt++)
          acc[mt][nt] = __builtin_amdgcn_mfma_f32_16x16x32_bf16(af[mt], bf[nt], acc[mt][nt], 0, 0, 0);
    }
  }
  #pragma unroll
  for(int mt=0;mt<4;mt++){
    #pragma unroll
    for(int nt=0;nt<4;nt++){
      int col = bn + wn + nt*16 + l15;
      float bv = bias ? bias[col] : 0.f;
      #pragma unroll
      for(int e=0;e<4;e++){
        int row = bm + wm + mt*16 + kg*4 + e;
        C[(size_t)row*N + col] = acc[mt][nt][e] + bv;
      }
    }
  }
}

// ------------- persistent 2-layer pipelined LSTM ---------------------------
// layer0 blocks [0,NB0): z = xw0[t] + h0prev@Ut0 + b0
// layer1 blocks [NB0,2*NB0): z = concat(h0seq[t], h1prev) @ WU1 + b1 (W folded)
// c-state lives in registers; h exchanged via global + grid barrier.
template<int HU>
__global__ __launch_bounds__(256, 1)
void k_rnn(const unsigned short* __restrict__ Ut0,   // [4HU][HU] packed
           const unsigned short* __restrict__ WU1,   // [4HU][2HU] packed
           const float* __restrict__ xw0,            // [B*T][4HU] packed
           const float* __restrict__ bpk0,
           const float* __restrict__ bpk1,
           const unsigned short* __restrict__ h0init,
           const unsigned short* __restrict__ h1init,
           const float* __restrict__ c0init,
           const float* __restrict__ c1init,
           unsigned short* h0seq,                    // [B*T][HU] bf16
           unsigned short* h1seq,
           float* __restrict__ c0fin,
           float* __restrict__ c1fin,
           unsigned* bar){
  constexpr int N4 = 4*HU;
  constexpr int NB0 = N4/128;
  const int blk = blockIdx.x;
  const int layer = (blk >= NB0) ? 1 : 0;
  const int cb = layer ? blk - NB0 : blk;
  const int tid = threadIdx.x;
  const int lane = tid & 63, w = tid >> 6;
  const int l15 = lane & 15, kg = lane >> 4;
  const int K = layer ? 2*HU : HU;
  const unsigned short* Um = layer ? WU1 : Ut0;
  const int c0col = cb*128 + w*32;
  const unsigned short* b0p = Um + (size_t)(c0col + l15)*K + kg*8;
  const unsigned short* b1p = Um + (size_t)(c0col + 16 + l15)*K + kg*8;
  const float* bpk = layer ? bpk1 : bpk0;
  unsigned short* hseq = layer ? h1seq : h0seq;
  const float* cinit = layer ? c1init : c0init;
  float* cfin = layer ? c1fin : c0fin;
  const unsigned nblk = gridDim.x;

  float4 bvr[2];
  int rr[2], pwr[2], pcr[2], hur[2], pgr[2];
  #pragma unroll
  for(int i=0;i<2;i++){
    int item = tid + i*256;
    rr[i] = item >> 5; int uu = item & 31;
    pwr[i] = uu >> 3; pcr[i] = (uu & 7)*4;
    hur[i] = cb*32 + uu;
    pgr[i] = cb*128 + uu*4;
    bvr[i] = *(const float4*)(bpk + pgr[i]);
  }
  float creg[2] = {0.f, 0.f};
  __shared__ float z[4][16][33];

  for(int it = 0; it <= T_; ++it){
    const int active = layer ? (it >= 1) : (it < T_);
    const int t = layer ? (it - 1) : it;
    if(active){
      f32x4 acc0 = {}, acc1 = {};
      const unsigned short* baseA; size_t strA;
      if(layer){ baseA = h0seq + (size_t)t*HU; strA = (size_t)T_*HU; }
      else if(t == 0){ baseA = h0init; strA = HU; }
      else { baseA = h0seq + (size_t)(t-1)*HU; strA = (size_t)T_*HU; }
      const unsigned short* aA = baseA + (size_t)l15*strA + kg*8;
      const unsigned short* aB = nullptr;
      if(layer){
        const unsigned short* baseB; size_t strB;
        if(t == 0){ baseB = h1init; strB = HU; }
        else { baseB = h1seq + (size_t)(t-1)*HU; strB = (size_t)T_*HU; }
        aB = baseB + (size_t)l15*strB + kg*8;
      }
      #pragma unroll 4
      for(int k0 = 0; k0 < K; k0 += 32){
        s16x8 a = (k0 < HU) ? *(const s16x8*)(aA + k0) : *(const s16x8*)(aB + (k0 - HU));
        s16x8 b0 = *(const s16x8*)(b0p + k0);
        s16x8 b1 = *(const s16x8*)(b1p + k0);
        acc0 = __builtin_amdgcn_mfma_f32_16x16x32_bf16(a, b0, acc0, 0, 0, 0);
        acc1 = __builtin_amdgcn_mfma_f32_16x16x32_bf16(a, b1, acc1, 0, 0, 0);
      }
      #pragma unroll
      for(int e=0;e<4;e++){
        int r = kg*4 + e;
        z[w][r][l15]      = acc0[e];
        z[w][r][16 + l15] = acc1[e];
      }
    }
    __syncthreads();
    if(active){
      #pragma unroll
      for(int i=0;i<2;i++){
        float zi = z[pwr[i]][rr[i]][pcr[i]];
        float zf = z[pwr[i]][rr[i]][pcr[i]+1];
        float zg = z[pwr[i]][rr[i]][pcr[i]+2];
        float zo = z[pwr[i]][rr[i]][pcr[i]+3];
        float si = zi + bvr[i].x, sf = zf + bvr[i].y;
        float sg = zg + bvr[i].z, so = zo + bvr[i].w;
        if(!layer){
          float4 xv = *(const float4*)(xw0 + (size_t)(rr[i]*T_ + t)*N4 + pgr[i]);
          si += xv.x; sf += xv.y; sg += xv.z; so += xv.w;
        }
        float cin = (t == 0) ? cinit[rr[i]*HU + hur[i]] : creg[i];
        float c2 = sigm(sf)*cin + sigm(si)*tanhf(sg);
        float h2 = sigm(so)*tanhf(c2);
        creg[i] = c2;
        hseq[(size_t)(rr[i]*T_ + t)*HU + hur[i]] = f2bf(h2);
        if(t == T_-1) cfin[rr[i]*HU + hur[i]] = c2;
      }
    }
    if(it < T_) gbar(bar, nblk);
  }
}

// ---------------------------------------------------------------------------
extern "C" void kernel_launch(void* const* d_in, const int* in_sizes, int n_in,
                              void* d_out, int out_size, void* d_ws, size_t ws_size,
                              hipStream_t stream){
  const int*   ids1 = (const int*)d_in[0];
  const int*   ids2 = (const int*)d_in[1];
  const float* init = (const float*)d_in[2];
  const float* emb  = (const float*)d_in[3];
  const float* W1_0 = (const float*)d_in[4];
  const float* U1_0 = (const float*)d_in[5];
  const float* b1_0 = (const float*)d_in[6];
  const float* W1_1 = (const float*)d_in[7];
  const float* U1_1 = (const float*)d_in[8];
  const float* b1_1 = (const float*)d_in[9];
  const float* W2_0 = (const float*)d_in[10];
  const float* U2_0 = (const float*)d_in[11];
  const float* b2_0 = (const float*)d_in[12];
  const float* W2_1 = (const float*)d_in[13];
  const float* U2_1 = (const float*)d_in[14];
  const float* b2_1 = (const float*)d_in[15];
  const float* Wp1  = (const float*)d_in[16];
  const float* bp1  = (const float*)d_in[17];
  const float* Wp2  = (const float*)d_in[18];
  const float* bp2  = (const float*)d_in[19];
  float* out1 = (float*)d_out;
  float* out2 = out1 + (size_t)B_*T_*V_;

  char* base = (char*)d_ws;
  float*          xw    = (float*)(base);                           // 16 MB
  unsigned short* ut0_1 = (unsigned short*)(base + (16u<<20));      // 2 MB
  unsigned short* wu1_1 = (unsigned short*)(base + (18u<<20));      // 4 MB
  unsigned short* ut0_2 = (unsigned short*)(base + (22u<<20));      // 8 MB
  unsigned short* wu1_2 = (unsigned short*)(base + (30u<<20));      // 16 MB
  unsigned short* wtmp  = (unsigned short*)(base + (46u<<20));      // 4 MB
  unsigned short* ebuf  = (unsigned short*)(base + (50u<<20));      // 1 MB
  unsigned short* h0s1  = (unsigned short*)(base + (51u<<20));      // 1 MB
  unsigned short* h1s1  = (unsigned short*)(base + (52u<<20));      // 1 MB
  unsigned short* h0s2  = (unsigned short*)(base + (53u<<20));      // 2 MB
  unsigned short* h1s2  = (unsigned short*)(base + (55u<<20));      // 2 MB
  char* M = base + (57u<<20);                                       // misc ~1MB
  unsigned short* h0i1 = (unsigned short*)(M);
  unsigned short* h1i1 = (unsigned short*)(M + 16384);
  float* c0i1 = (float*)(M + 32768);
  float* c1i1 = (float*)(M + 65536);
  unsigned short* h2i0 = (unsigned short*)(M + 98304);
  unsigned short* h2i1 = (unsigned short*)(M + 131072);
  float* c2i0 = (float*)(M + 163840);
  float* c2i1 = (float*)(M + 229376);
  float* c0f1 = (float*)(M + 294912);
  float* c1f1 = (float*)(M + 327680);
  float* c0f2 = (float*)(M + 360448);
  float* c1f2 = (float*)(M + 425984);
  float* bpk10 = (float*)(M + 491520);
  float* bpk11 = (float*)(M + 499712);
  float* bpk20 = (float*)(M + 507904);
  float* bpk21 = (float*)(M + 524288);
  unsigned* bar = (unsigned*)(M + 540672);
  unsigned short* wpT = (unsigned short*)(base + (58u<<20));        // 65.6 MB
  const size_t NEED_ALL = ((size_t)58u<<20) + (size_t)V_*1024*2;
  const bool wide = ws_size >= NEED_ALL;

  k_barinit<<<dim3(1), dim3(1), 0, stream>>>(bar);

  // ================= RNN1 =================
  k_init1<<<dim3(32), dim3(256), 0, stream>>>(init, h0i1, c0i1, h1i1, c1i1);
  k_gather<<<dim3(B_*T_), dim3(128), 0, stream>>>(ids1, emb, ebuf);
  k_tcvt<<<dim3(64, 16), dim3(256), 0, stream>>>(U1_0, ut0_1, 2048, 512, 512, 0);
  k_tcvt<<<dim3(64, 16), dim3(256), 0, stream>>>(W1_0, wtmp,  2048, 512, 512, 0);
  k_tcvt<<<dim3(64, 16), dim3(256), 0, stream>>>(W1_1, wu1_1, 2048, 512, 1024, 0);
  k_tcvt<<<dim3(64, 16), dim3(256), 0, stream>>>(U1_1, wu1_1, 2048, 512, 1024, 512);
  k_bpack<<<dim3(8),  dim3(256), 0, stream>>>(b1_0, bpk10, 512, 2048);
  k_bpack<<<dim3(8),  dim3(256), 0, stream>>>(b1_1, bpk11, 512, 2048);
  k_mm<0><<<dim3(16, 8), dim3(256), 0, stream>>>(ebuf, wtmp, nullptr, xw, 1024, 2048, 512);
  k_rnn<512><<<dim3(32), dim3(256), 0, stream>>>(ut0_1, wu1_1, xw, bpk10, bpk11,
      h0i1, h1i1, c0i1, c1i1, h0s1, h1s1, c0f1, c1f1, bar);
  // projection 1
  if(wide){
    k_tcvt<<<dim3(1000, 16), dim3(256), 0, stream>>>(Wp1, wpT, V_, 0, 512, 0);
    k_mm<0><<<dim3(250, 8), dim3(256), 0, stream>>>(h1s1, wpT, bp1, out1, 1024, V_, 512);
  } else {
    k_mm<1><<<dim3(250, 8), dim3(256), 0, stream>>>(h1s1, Wp1, bp1, out1, 1024, V_, 512);
  }

  // ================= RNN2 =================
  k_init2<<<dim3(64, 2), dim3(256), 0, stream>>>(init, h0s1, h1s1, c0f1, c1f1,
                                                 h2i0, h2i1, c2i0, c2i1);
  k_gather<<<dim3(B_*T_), dim3(128), 0, stream>>>(ids2, emb, ebuf);
  k_tcvt<<<dim3(128, 32), dim3(256), 0, stream>>>(U2_0, ut0_2, 4096, 1024, 1024, 0);
  k_tcvt<<<dim3(128, 16), dim3(256), 0, stream>>>(W2_0, wtmp,  4096, 1024, 512, 0);
  k_tcvt<<<dim3(128, 32), dim3(256), 0, stream>>>(W2_1, wu1_2, 4096, 1024, 2048, 0);
  k_tcvt<<<dim3(128, 32), dim3(256), 0, stream>>>(U2_1, wu1_2, 4096, 1024, 2048, 1024);
  k_bpack<<<dim3(16), dim3(256), 0, stream>>>(b2_0, bpk20, 1024, 4096);
  k_bpack<<<dim3(16), dim3(256), 0, stream>>>(b2_1, bpk21, 1024, 4096);
  k_mm<0><<<dim3(32, 8), dim3(256), 0, stream>>>(ebuf, wtmp, nullptr, xw, 1024, 4096, 512);
  k_rnn<1024><<<dim3(64), dim3(256), 0, stream>>>(ut0_2, wu1_2, xw, bpk20, bpk21,
      h2i0, h2i1, c2i0, c2i1, h0s2, h1s2, c0f2, c1f2, bar);
  // projection 2
  if(wide){
    k_tcvt<<<dim3(1000, 32), dim3(256), 0, stream>>>(Wp2, wpT, V_, 0, 1024, 0);
    k_mm<0><<<dim3(250, 8), dim3(256), 0, stream>>>(h1s2, wpT, bp2, out2, 1024, V_, 1024);
  } else {
    k_mm<1><<<dim3(250, 8), dim3(256), 0, stream>>>(h1s2, Wp2, bp2, out2, 1024, V_, 1024);
  }
}

// Round 4
// 2139.303 us; speedup vs baseline: 2.8191x; 1.5784x over previous
//
#include <hip/hip_runtime.h>
#include <hip/hip_bf16.h>

#define B_ 16
#define T_ 64
#define E_ 512
#define H_ 512
#define V_ 32000

typedef __attribute__((ext_vector_type(4))) float f32x4;
typedef __attribute__((ext_vector_type(8))) short s16x8;

__device__ __forceinline__ float sigm(float x){ return 1.0f/(1.0f + __expf(-x)); }

__device__ __forceinline__ unsigned short f2bf(float x){
  unsigned int u = __float_as_uint(x);
  return (unsigned short)((u + 0x7FFFu + ((u>>16)&1u)) >> 16);
}

// ---- grid barrier: RELAXED spin (no L2-inv per poll), one ACQUIRE at exit --
__device__ __forceinline__ void gbar(unsigned* bar, unsigned nblk){
  __syncthreads();
  if(threadIdx.x == 0){
    __threadfence();   // release: write back L2 so h-writes reach fabric
    unsigned g = __hip_atomic_load(bar+1, __ATOMIC_RELAXED, __HIP_MEMORY_SCOPE_AGENT);
    unsigned a = __hip_atomic_fetch_add(bar, 1u, __ATOMIC_RELAXED, __HIP_MEMORY_SCOPE_AGENT);
    if(a == nblk-1u){
      __hip_atomic_store(bar, 0u, __ATOMIC_RELAXED, __HIP_MEMORY_SCOPE_AGENT);
      __hip_atomic_store(bar+1, g+1u, __ATOMIC_RELEASE, __HIP_MEMORY_SCOPE_AGENT);
    } else {
      unsigned sp = 0, cur;
      do {
        cur = ((sp++ & 255u) == 255u)
            ? __hip_atomic_load(bar+1, __ATOMIC_ACQUIRE, __HIP_MEMORY_SCOPE_AGENT)
            : __hip_atomic_load(bar+1, __ATOMIC_RELAXED, __HIP_MEMORY_SCOPE_AGENT);
        if(cur != g) break;
        __builtin_amdgcn_s_sleep(4);
      } while(1);
    }
    (void)__hip_atomic_load(bar+1, __ATOMIC_ACQUIRE, __HIP_MEMORY_SCOPE_AGENT); // inv caches once
  }
  __syncthreads();
}

__global__ void k_barinit(unsigned* bar){ bar[0] = 0u; bar[1] = 0u; }

// ------------- embedding gather -> bf16 [1024][512] ------------------------
__global__ void k_gather(const int* __restrict__ ids, const float* __restrict__ emb,
                         unsigned short* __restrict__ out){
  const int row = blockIdx.x;
  const int id  = ids[row];
  float4 v = *(const float4*)(emb + (size_t)id*E_ + threadIdx.x*4);
  ushort4 o;
  o.x = f2bf(v.x); o.y = f2bf(v.y); o.z = f2bf(v.z); o.w = f2bf(v.w);
  *(ushort4*)(out + (size_t)row*E_ + threadIdx.x*4) = o;
}

// ------------- transpose+convert(+permute)(+swizzle) -----------------------
// f32 [Ksrc][N] -> bf16 [N][Kfull]; row p(n)=(n%Hp)*4+n/Hp when Hp>0.
// swz: XOR-permute 16B slots within each 128B chunk by (p&7)  (for k_rnn LDS).
__global__ __launch_bounds__(256)
void k_tcvt(const float* __restrict__ in, unsigned short* __restrict__ out,
            int N, int Hp, int Kfull, int koff, int swz){
  __shared__ float tile[32][33];
  const int n0 = blockIdx.x*32, k0 = blockIdx.y*32;
  const int x = threadIdx.x & 31, y = threadIdx.x >> 5;
  #pragma unroll
  for(int i=0;i<4;i++){
    int k = y + i*8;
    tile[k][x] = in[(size_t)(k0+k)*N + n0 + x];
  }
  __syncthreads();
  #pragma unroll
  for(int i=0;i<4;i++){
    int nl = y + i*8;
    int n  = n0 + nl;
    int p  = Hp ? ((n % Hp)*4 + n / Hp) : n;
    int kk = koff + k0 + x;
    size_t idx;
    if(swz){
      int k2 = kk*2;
      int slot = ((k2>>4)&7) ^ (p&7);
      idx = (size_t)p*Kfull + (((k2 & ~127) | (slot<<4) | (k2 & 15)) >> 1);
    } else {
      idx = (size_t)p*Kfull + kk;
    }
    out[idx] = f2bf(tile[x][nl]);
  }
}

// ------------- bias permute: bpk[p] = b[(p&3)*H + (p>>2)] -------------------
__global__ void k_bpack(const float* __restrict__ b, float* __restrict__ out, int H, int N){
  int p = blockIdx.x*256 + threadIdx.x;
  if(p < N) out[p] = b[(p&3)*H + (p>>2)];
}

// ------------- init states --------------------------------------------------
__global__ void k_init1(const float* __restrict__ init_state,
                        unsigned short* h0i, float* c0i, unsigned short* h1i, float* c1i){
  int i = blockIdx.x*256 + threadIdx.x;
  if(i >= B_*H_) return;
  float v0 = init_state[i];
  float v1 = init_state[B_*H_ + i];
  h0i[i] = f2bf(v0); c0i[i] = v0;
  h1i[i] = f2bf(v1); c1i[i] = v1;
}

__global__ void k_init2(const float* __restrict__ init_state,
                        const unsigned short* __restrict__ h0seq1,
                        const unsigned short* __restrict__ h1seq1,
                        const float* __restrict__ c0f1, const float* __restrict__ c1f1,
                        unsigned short* h20i, unsigned short* h21i,
                        float* c20i, float* c21i){
  const int l = blockIdx.y;
  int i = blockIdx.x*256 + threadIdx.x;
  if(i >= B_*2*H_) return;
  const int r = i >> 10, j = i & 1023;
  unsigned short* ho = l ? h21i : h20i;
  float* co = l ? c21i : c20i;
  if(j < H_){
    float v = init_state[(size_t)l*B_*H_ + r*H_ + j];
    ho[i] = f2bf(v); co[i] = v;
  } else {
    const unsigned short* hs = l ? h1seq1 : h0seq1;
    const float* cf = l ? c1f1 : c0f1;
    ho[i] = hs[(size_t)(r*T_ + (T_-1))*H_ + (j - H_)];
    co[i] = cf[r*H_ + (j - H_)];
  }
}

// ------------- MFMA GEMM: C[M][N] = A[M][K](bf16) @ B + bias ---------------
template<int BF32>
__global__ __launch_bounds__(256)
void k_mm(const unsigned short* __restrict__ A, const void* __restrict__ Bsrc,
          const float* __restrict__ bias, float* __restrict__ C,
          int M, int N, int K){
  __shared__ __align__(16) unsigned short As[128*64];
  __shared__ __align__(16) unsigned short Bs[128*64];
  const int tid = threadIdx.x;
  const int lane = tid & 63, w = tid >> 6;
  const int wm = (w>>1)*64, wn = (w&1)*64;
  const int bm = blockIdx.y*128, bn = blockIdx.x*128;
  const int l15 = lane & 15, kg = lane >> 4;
  f32x4 acc[4][4] = {};

  for(int k0=0; k0<K; k0+=64){
    __syncthreads();
    #pragma unroll
    for(int ch=0; ch<4; ch++){
      int off = ch*4096 + tid*16;
      int row = off >> 7;
      int s   = ((off >> 4) & 7) ^ (row & 7);
      __builtin_amdgcn_global_load_lds(
        (const __attribute__((address_space(1))) unsigned int*)(A + (size_t)(bm+row)*K + k0 + s*8),
        (__attribute__((address_space(3))) unsigned int*)((char*)As + off), 16, 0, 0);
    }
    if(BF32){
      const float* Bf = (const float*)Bsrc;
      #pragma unroll
      for(int i=0;i<8;i++){
        int kl = (tid>>5) + i*8;
        int nl = (tid&31)*4;
        float4 v = *(const float4*)(Bf + (size_t)(k0+kl)*N + bn + nl);
        int slot = kl >> 3, kb = kl & 7;
        float vv[4] = {v.x, v.y, v.z, v.w};
        #pragma unroll
        for(int jj=0;jj<4;jj++){
          int n = nl + jj;
          Bs[n*64 + ((slot ^ (n&7))*8) + kb] = f2bf(vv[jj]);
        }
      }
    } else {
      const unsigned short* Bt = (const unsigned short*)Bsrc;
      #pragma unroll
      for(int ch=0; ch<4; ch++){
        int off = ch*4096 + tid*16;
        int row = off >> 7;
        int s   = ((off >> 4) & 7) ^ (row & 7);
        __builtin_amdgcn_global_load_lds(
          (const __attribute__((address_space(1))) unsigned int*)(Bt + (size_t)(bn+row)*K + k0 + s*8),
          (__attribute__((address_space(3))) unsigned int*)((char*)Bs + off), 16, 0, 0);
      }
    }
    __syncthreads();

    #pragma unroll
    for(int q=0;q<2;q++){
      s16x8 af[4], bf[4];
      #pragma unroll
      for(int mt=0;mt<4;mt++){
        int row = wm + mt*16 + l15;
        int s = (q*4 + kg) ^ (row & 7);
        af[mt] = *(const s16x8*)(As + row*64 + s*8);
      }
      #pragma unroll
      for(int nt=0;nt<4;nt++){
        int row = wn + nt*16 + l15;
        int s = (q*4 + kg) ^ (row & 7);
        bf[nt] = *(const s16x8*)(Bs + row*64 + s*8);
      }
      #pragma unroll
      for(int mt=0;mt<4;mt++)
        #pragma unroll
        for(int nt=0;nt<4;nt++)
          acc[mt][nt] = __builtin_amdgcn_mfma_f32_16x16x32_bf16(af[mt], bf[nt], acc[mt][nt], 0, 0, 0);
    }
  }
  #pragma unroll
  for(int mt=0;mt<4;mt++){
    #pragma unroll
    for(int nt=0;nt<4;nt++){
      int col = bn + wn + nt*16 + l15;
      float bv = bias ? bias[col] : 0.f;
      #pragma unroll
      for(int e=0;e<4;e++){
        int row = bm + wm + mt*16 + kg*4 + e;
        C[(size_t)row*N + col] = acc[mt][nt][e] + bv;
      }
    }
  }
}

// ------------- persistent 2-layer LSTM, U resident in LDS ------------------
// Block owns C gate-cols (C/4 units). 4 waves split K; LDS f32 reduce; fused gates.
template<int C, int K, int LAYER, int HU>
__device__ __forceinline__ void rnn_body(
    unsigned short* __restrict__ Uld, float* __restrict__ zp,
    const unsigned short* __restrict__ Uslice,
    const float* __restrict__ xw0, const float* __restrict__ bpk,
    const unsigned short* __restrict__ h0init, const unsigned short* __restrict__ h1init,
    const float* __restrict__ cinit,
    unsigned short* __restrict__ h0seq, unsigned short* __restrict__ h1seq,
    float* __restrict__ cfin, unsigned* bar, int cb, unsigned nblk)
{
  constexpr int KW = K/4, KS = KW/32, FR = C/16, UB = C/4;
  constexpr int K2 = K*2;
  constexpr int ITEMS = 16*UB;
  const int tid = threadIdx.x;
  const int lane = tid & 63, w = tid >> 6;
  const int l15 = lane & 15, kg = lane >> 4;

  // stage this block's U slice into LDS (linear copy; buffer pre-swizzled)
  constexpr int CP = (C*K2)/4096;
  #pragma unroll
  for(int i=0;i<CP;i++){
    __builtin_amdgcn_global_load_lds(
      (const __attribute__((address_space(1))) unsigned int*)((const char*)Uslice + i*4096 + tid*16),
      (__attribute__((address_space(3))) unsigned int*)((char*)Uld + i*4096 + tid*16), 16, 0, 0);
  }
  const int base_p = cb*C;
  const int base_u = cb*UB;
  float4 bvr = make_float4(0.f,0.f,0.f,0.f);
  int er = 0, eu = 0;
  if(tid < ITEMS){ er = tid / UB; eu = tid - er*UB; bvr = *(const float4*)(bpk + base_p + eu*4); }
  float creg = 0.f;
  unsigned short* hseqW = LAYER ? h1seq : h0seq;

  int cbyte[FR], cx[FR];
  #pragma unroll
  for(int f=0;f<FR;f++){ int c = f*16 + l15; cbyte[f] = c*K2; cx[f] = (c&7)<<4; }

  __syncthreads();   // drains global_load_lds (vmcnt) + block sync

  for(int it = 0; it <= T_; ++it){
    const bool active = LAYER ? (it >= 1) : (it < T_);
    const int t = LAYER ? it-1 : it;
    if(active){
      const unsigned short* asrc;
      if constexpr(LAYER == 0){
        asrc = (t == 0) ? (h0init + l15*HU)
                        : (h0seq + ((size_t)(l15*T_ + (t-1)))*HU);
      } else {
        if(w < 2){
          asrc = h0seq + ((size_t)(l15*T_ + t))*HU;           // k in [0,HU)
        } else {
          asrc = ((t == 0) ? (h1init + l15*HU)
                           : (h1seq + ((size_t)(l15*T_ + (t-1)))*HU)) - HU; // k in [HU,2HU)
        }
      }
      f32x4 acc[FR];
      #pragma unroll
      for(int f=0;f<FR;f++) acc[f] = (f32x4){0.f,0.f,0.f,0.f};
      #pragma unroll
      for(int s=0;s<KS;s++){
        const int kel = w*KW + s*32 + kg*8;
        s16x8 a = *(const s16x8*)(asrc + kel);
        const int kb  = kel*2;
        const int kch = kb & ~127;
        const int ksl = (kb >> 4) & 7;
        #pragma unroll
        for(int f=0;f<FR;f++){
          const int ad = cbyte[f] + kch + ((ksl<<4) ^ cx[f]);
          s16x8 b = *(const s16x8*)((const char*)Uld + ad);
          acc[f] = __builtin_amdgcn_mfma_f32_16x16x32_bf16(a, b, acc[f], 0, 0, 0);
        }
      }
      #pragma unroll
      for(int f=0;f<FR;f++)
        #pragma unroll
        for(int e=0;e<4;e++)
          zp[(w*16 + kg*4 + e)*68 + f*16 + l15] = acc[f][e];
    }
    __syncthreads();
    if(active && tid < ITEMS){
      float4 z0 = *(const float4*)(zp + (     er)*68 + eu*4);
      float4 z1 = *(const float4*)(zp + (16 + er)*68 + eu*4);
      float4 z2 = *(const float4*)(zp + (32 + er)*68 + eu*4);
      float4 z3 = *(const float4*)(zp + (48 + er)*68 + eu*4);
      float si = z0.x+z1.x+z2.x+z3.x + bvr.x;
      float sf = z0.y+z1.y+z2.y+z3.y + bvr.y;
      float sg = z0.z+z1.z+z2.z+z3.z + bvr.z;
      float so = z0.w+z1.w+z2.w+z3.w + bvr.w;
      if constexpr(LAYER == 0){
        float4 xv = *(const float4*)(xw0 + ((size_t)(er*T_ + t))*(4*HU) + base_p + eu*4);
        si += xv.x; sf += xv.y; sg += xv.z; so += xv.w;
      }
      float cin = (t == 0) ? cinit[er*HU + base_u + eu] : creg;
      float c2 = sigm(sf)*cin + sigm(si)*tanhf(sg);
      float h2 = sigm(so)*tanhf(c2);
      creg = c2;
      hseqW[((size_t)(er*T_ + t))*HU + base_u + eu] = f2bf(h2);
      if(t == T_-1) cfin[er*HU + base_u + eu] = c2;
    }
    if(it < T_) gbar(bar, nblk);
  }
}

template<int HU, int C0, int C1>
__global__ __launch_bounds__(256, 1)
void k_rnn(const unsigned short* __restrict__ Ut0, const unsigned short* __restrict__ WU1,
           const float* __restrict__ xw0, const float* __restrict__ bpk0, const float* __restrict__ bpk1,
           const unsigned short* __restrict__ h0init, const unsigned short* __restrict__ h1init,
           const float* __restrict__ c0init, const float* __restrict__ c1init,
           unsigned short* __restrict__ h0seq, unsigned short* __restrict__ h1seq,
           float* __restrict__ c0fin, float* __restrict__ c1fin, unsigned* bar)
{
  constexpr int NB0 = 4*HU/C0;
  constexpr int UMAXE = (C0*HU > C1*2*HU) ? C0*HU : C1*2*HU;
  __shared__ __align__(16) unsigned short Uld[UMAXE];   // 128 KB
  __shared__ __align__(16) float zred[64*68];           // 17 KB
  const unsigned nblk = gridDim.x;
  const int blk = blockIdx.x;
  if(blk < NB0)
    rnn_body<C0, HU, 0, HU>(Uld, zred, Ut0 + (size_t)blk*C0*HU, xw0, bpk0,
                            h0init, h1init, c0init, h0seq, h1seq, c0fin, bar, blk, nblk);
  else
    rnn_body<C1, 2*HU, 1, HU>(Uld, zred, WU1 + (size_t)(blk-NB0)*C1*2*HU, nullptr, bpk1,
                            h0init, h1init, c1init, h0seq, h1seq, c1fin, bar, blk-NB0, nblk);
}

// ---------------------------------------------------------------------------
extern "C" void kernel_launch(void* const* d_in, const int* in_sizes, int n_in,
                              void* d_out, int out_size, void* d_ws, size_t ws_size,
                              hipStream_t stream){
  const int*   ids1 = (const int*)d_in[0];
  const int*   ids2 = (const int*)d_in[1];
  const float* init = (const float*)d_in[2];
  const float* emb  = (const float*)d_in[3];
  const float* W1_0 = (const float*)d_in[4];
  const float* U1_0 = (const float*)d_in[5];
  const float* b1_0 = (const float*)d_in[6];
  const float* W1_1 = (const float*)d_in[7];
  const float* U1_1 = (const float*)d_in[8];
  const float* b1_1 = (const float*)d_in[9];
  const float* W2_0 = (const float*)d_in[10];
  const float* U2_0 = (const float*)d_in[11];
  const float* b2_0 = (const float*)d_in[12];
  const float* W2_1 = (const float*)d_in[13];
  const float* U2_1 = (const float*)d_in[14];
  const float* b2_1 = (const float*)d_in[15];
  const float* Wp1  = (const float*)d_in[16];
  const float* bp1  = (const float*)d_in[17];
  const float* Wp2  = (const float*)d_in[18];
  const float* bp2  = (const float*)d_in[19];
  float* out1 = (float*)d_out;
  float* out2 = out1 + (size_t)B_*T_*V_;

  char* base = (char*)d_ws;
  float*          xw    = (float*)(base);                           // 16 MB
  unsigned short* ut0_1 = (unsigned short*)(base + (16u<<20));      // 2 MB  [2048][512] swz
  unsigned short* wu1_1 = (unsigned short*)(base + (18u<<20));      // 4 MB  [2048][1024] swz
  unsigned short* ut0_2 = (unsigned short*)(base + (22u<<20));      // 8 MB  [4096][1024] swz
  unsigned short* wu1_2 = (unsigned short*)(base + (30u<<20));      // 16 MB [4096][2048] swz
  unsigned short* wtmp  = (unsigned short*)(base + (46u<<20));      // 4 MB  plain
  unsigned short* ebuf  = (unsigned short*)(base + (50u<<20));      // 1 MB
  unsigned short* h0s1  = (unsigned short*)(base + (51u<<20));      // 1 MB
  unsigned short* h1s1  = (unsigned short*)(base + (52u<<20));      // 1 MB
  unsigned short* h0s2  = (unsigned short*)(base + (53u<<20));      // 2 MB
  unsigned short* h1s2  = (unsigned short*)(base + (55u<<20));      // 2 MB
  char* M = base + (57u<<20);
  unsigned short* h0i1 = (unsigned short*)(M);
  unsigned short* h1i1 = (unsigned short*)(M + 16384);
  float* c0i1 = (float*)(M + 32768);
  float* c1i1 = (float*)(M + 65536);
  unsigned short* h2i0 = (unsigned short*)(M + 98304);
  unsigned short* h2i1 = (unsigned short*)(M + 131072);
  float* c2i0 = (float*)(M + 163840);
  float* c2i1 = (float*)(M + 229376);
  float* c0f1 = (float*)(M + 294912);
  float* c1f1 = (float*)(M + 327680);
  float* c0f2 = (float*)(M + 360448);
  float* c1f2 = (float*)(M + 425984);
  float* bpk10 = (float*)(M + 491520);
  float* bpk11 = (float*)(M + 499712);
  float* bpk20 = (float*)(M + 507904);
  float* bpk21 = (float*)(M + 524288);
  unsigned* bar = (unsigned*)(M + 540672);
  unsigned short* wpT = (unsigned short*)(base + (58u<<20));        // 65.6 MB
  const size_t NEED_ALL = ((size_t)58u<<20) + (size_t)V_*1024*2;
  const bool wide = ws_size >= NEED_ALL;

  k_barinit<<<dim3(1), dim3(1), 0, stream>>>(bar);

  // ================= RNN1 =================
  k_init1<<<dim3(32), dim3(256), 0, stream>>>(init, h0i1, c0i1, h1i1, c1i1);
  k_gather<<<dim3(B_*T_), dim3(128), 0, stream>>>(ids1, emb, ebuf);
  k_tcvt<<<dim3(64, 16), dim3(256), 0, stream>>>(U1_0, ut0_1, 2048, 512, 512, 0, 1);
  k_tcvt<<<dim3(64, 16), dim3(256), 0, stream>>>(W1_0, wtmp,  2048, 512, 512, 0, 0);
  k_tcvt<<<dim3(64, 16), dim3(256), 0, stream>>>(W1_1, wu1_1, 2048, 512, 1024, 0, 1);
  k_tcvt<<<dim3(64, 16), dim3(256), 0, stream>>>(U1_1, wu1_1, 2048, 512, 1024, 512, 1);
  k_bpack<<<dim3(8),  dim3(256), 0, stream>>>(b1_0, bpk10, 512, 2048);
  k_bpack<<<dim3(8),  dim3(256), 0, stream>>>(b1_1, bpk11, 512, 2048);
  k_mm<0><<<dim3(16, 8), dim3(256), 0, stream>>>(ebuf, wtmp, nullptr, xw, 1024, 2048, 512);
  k_rnn<512, 64, 64><<<dim3(64), dim3(256), 0, stream>>>(ut0_1, wu1_1, xw, bpk10, bpk11,
      h0i1, h1i1, c0i1, c1i1, h0s1, h1s1, c0f1, c1f1, bar);
  // projection 1
  if(wide){
    k_tcvt<<<dim3(1000, 16), dim3(256), 0, stream>>>(Wp1, wpT, V_, 0, 512, 0, 0);
    k_mm<0><<<dim3(250, 8), dim3(256), 0, stream>>>(h1s1, wpT, bp1, out1, 1024, V_, 512);
  } else {
    k_mm<1><<<dim3(250, 8), dim3(256), 0, stream>>>(h1s1, Wp1, bp1, out1, 1024, V_, 512);
  }

  // ================= RNN2 =================
  k_init2<<<dim3(64, 2), dim3(256), 0, stream>>>(init, h0s1, h1s1, c0f1, c1f1,
                                                 h2i0, h2i1, c2i0, c2i1);
  k_gather<<<dim3(B_*T_), dim3(128), 0, stream>>>(ids2, emb, ebuf);
  k_tcvt<<<dim3(128, 32), dim3(256), 0, stream>>>(U2_0, ut0_2, 4096, 1024, 1024, 0, 1);
  k_tcvt<<<dim3(128, 16), dim3(256), 0, stream>>>(W2_0, wtmp,  4096, 1024, 512, 0, 0);
  k_tcvt<<<dim3(128, 32), dim3(256), 0, stream>>>(W2_1, wu1_2, 4096, 1024, 2048, 0, 1);
  k_tcvt<<<dim3(128, 32), dim3(256), 0, stream>>>(U2_1, wu1_2, 4096, 1024, 2048, 1024, 1);
  k_bpack<<<dim3(16), dim3(256), 0, stream>>>(b2_0, bpk20, 1024, 4096);
  k_bpack<<<dim3(16), dim3(256), 0, stream>>>(b2_1, bpk21, 1024, 4096);
  k_mm<0><<<dim3(32, 8), dim3(256), 0, stream>>>(ebuf, wtmp, nullptr, xw, 1024, 4096, 512);
  k_rnn<1024, 64, 32><<<dim3(192), dim3(256), 0, stream>>>(ut0_2, wu1_2, xw, bpk20, bpk21,
      h2i0, h2i1, c2i0, c2i1, h0s2, h1s2, c0f2, c1f2, bar);
  // projection 2
  if(wide){
    k_tcvt<<<dim3(1000, 32), dim3(256), 0, stream>>>(Wp2, wpT, V_, 0, 1024, 0, 0);
    k_mm<0><<<dim3(250, 8), dim3(256), 0, stream>>>(h1s2, wpT, bp2, out2, 1024, V_, 1024);
  } else {
    k_mm<1><<<dim3(250, 8), dim3(256), 0, stream>>>(h1s2, Wp2, bp2, out2, 1024, V_, 1024);
  }
}

// Round 5
// 2064.226 us; speedup vs baseline: 2.9216x; 1.0364x over previous
//
#include <hip/hip_runtime.h>
#include <hip/hip_bf16.h>

#define B_ 16
#define T_ 64
#define E_ 512
#define H_ 512
#define V_ 32000

typedef __attribute__((ext_vector_type(4))) float f32x4;
typedef __attribute__((ext_vector_type(8))) short s16x8;

__device__ __forceinline__ float sigm(float x){ return 1.0f/(1.0f + __expf(-x)); }

__device__ __forceinline__ unsigned short f2bf(float x){
  unsigned int u = __float_as_uint(x);
  return (unsigned short)((u + 0x7FFFu + ((u>>16)&1u)) >> 16);
}

// ---- coherent (device-scope) load: reads coherence point, NO cache inv ----
__device__ __forceinline__ unsigned load_coh(const unsigned* p){
  unsigned v;
  asm volatile("global_load_dword %0, %1, off sc0 sc1\n\ts_waitcnt vmcnt(0)"
               : "=v"(v) : "v"(p) : "memory");
  return v;
}

// ---- grid barrier: coherent-load spin, single ACQUIRE (L2 inv) at exit ----
__device__ __forceinline__ void gbar(unsigned* bar, unsigned nblk){
  __syncthreads();
  if(threadIdx.x == 0){
    __threadfence();   // release: h-writes reach coherence point
    unsigned g = load_coh(bar+1);
    unsigned a = __hip_atomic_fetch_add(bar, 1u, __ATOMIC_RELAXED, __HIP_MEMORY_SCOPE_AGENT);
    if(a == nblk-1u){
      __hip_atomic_store(bar, 0u, __ATOMIC_RELAXED, __HIP_MEMORY_SCOPE_AGENT);
      __hip_atomic_store(bar+1, g+1u, __ATOMIC_RELEASE, __HIP_MEMORY_SCOPE_AGENT);
    } else {
      while(load_coh(bar+1) == g) __builtin_amdgcn_s_sleep(1);
    }
    (void)__hip_atomic_load(bar+1, __ATOMIC_ACQUIRE, __HIP_MEMORY_SCOPE_AGENT); // one inv
  }
  __syncthreads();
}

__global__ void k_barinit(unsigned* bar){ bar[0] = 0u; bar[1] = 0u; }

// ------------- embedding gather -> bf16 [1024][512] ------------------------
__global__ void k_gather(const int* __restrict__ ids, const float* __restrict__ emb,
                         unsigned short* __restrict__ out){
  const int row = blockIdx.x;
  const int id  = ids[row];
  float4 v = *(const float4*)(emb + (size_t)id*E_ + threadIdx.x*4);
  ushort4 o;
  o.x = f2bf(v.x); o.y = f2bf(v.y); o.z = f2bf(v.z); o.w = f2bf(v.w);
  *(ushort4*)(out + (size_t)row*E_ + threadIdx.x*4) = o;
}

// ------------- transpose+convert(+permute)(+swizzle) -----------------------
__global__ __launch_bounds__(256)
void k_tcvt(const float* __restrict__ in, unsigned short* __restrict__ out,
            int N, int Hp, int Kfull, int koff, int swz){
  __shared__ float tile[32][33];
  const int n0 = blockIdx.x*32, k0 = blockIdx.y*32;
  const int x = threadIdx.x & 31, y = threadIdx.x >> 5;
  #pragma unroll
  for(int i=0;i<4;i++){
    int k = y + i*8;
    tile[k][x] = in[(size_t)(k0+k)*N + n0 + x];
  }
  __syncthreads();
  #pragma unroll
  for(int i=0;i<4;i++){
    int nl = y + i*8;
    int n  = n0 + nl;
    int p  = Hp ? ((n % Hp)*4 + n / Hp) : n;
    int kk = koff + k0 + x;
    size_t idx;
    if(swz){
      int k2 = kk*2;
      int slot = ((k2>>4)&7) ^ (p&7);
      idx = (size_t)p*Kfull + (((k2 & ~127) | (slot<<4) | (k2 & 15)) >> 1);
    } else {
      idx = (size_t)p*Kfull + kk;
    }
    out[idx] = f2bf(tile[x][nl]);
  }
}

// ------------- bias permute: bpk[p] = b[(p&3)*H + (p>>2)] -------------------
__global__ void k_bpack(const float* __restrict__ b, float* __restrict__ out, int H, int N){
  int p = blockIdx.x*256 + threadIdx.x;
  if(p < N) out[p] = b[(p&3)*H + (p>>2)];
}

// ------------- init states --------------------------------------------------
__global__ void k_init1(const float* __restrict__ init_state,
                        unsigned short* h0i, float* c0i, unsigned short* h1i, float* c1i){
  int i = blockIdx.x*256 + threadIdx.x;
  if(i >= B_*H_) return;
  float v0 = init_state[i];
  float v1 = init_state[B_*H_ + i];
  h0i[i] = f2bf(v0); c0i[i] = v0;
  h1i[i] = f2bf(v1); c1i[i] = v1;
}

__global__ void k_init2(const float* __restrict__ init_state,
                        const unsigned short* __restrict__ h0seq1,
                        const unsigned short* __restrict__ h1seq1,
                        const float* __restrict__ c0f1, const float* __restrict__ c1f1,
                        unsigned short* h20i, unsigned short* h21i,
                        float* c20i, float* c21i){
  const int l = blockIdx.y;
  int i = blockIdx.x*256 + threadIdx.x;
  if(i >= B_*2*H_) return;
  const int r = i >> 10, j = i & 1023;
  unsigned short* ho = l ? h21i : h20i;
  float* co = l ? c21i : c20i;
  if(j < H_){
    float v = init_state[(size_t)l*B_*H_ + r*H_ + j];
    ho[i] = f2bf(v); co[i] = v;
  } else {
    const unsigned short* hs = l ? h1seq1 : h0seq1;
    const float* cf = l ? c1f1 : c0f1;
    ho[i] = hs[(size_t)(r*T_ + (T_-1))*H_ + (j - H_)];
    co[i] = cf[r*H_ + (j - H_)];
  }
}

// ------------- MFMA GEMM: C[M][N] = A[M][K](bf16) @ B + bias ---------------
template<int BF32>
__global__ __launch_bounds__(256)
void k_mm(const unsigned short* __restrict__ A, const void* __restrict__ Bsrc,
          const float* __restrict__ bias, float* __restrict__ C,
          int M, int N, int K){
  __shared__ __align__(16) unsigned short As[128*64];
  __shared__ __align__(16) unsigned short Bs[128*64];
  const int tid = threadIdx.x;
  const int lane = tid & 63, w = tid >> 6;
  const int wm = (w>>1)*64, wn = (w&1)*64;
  const int bm = blockIdx.y*128, bn = blockIdx.x*128;
  const int l15 = lane & 15, kg = lane >> 4;
  f32x4 acc[4][4] = {};

  for(int k0=0; k0<K; k0+=64){
    __syncthreads();
    #pragma unroll
    for(int ch=0; ch<4; ch++){
      int off = ch*4096 + tid*16;
      int row = off >> 7;
      int s   = ((off >> 4) & 7) ^ (row & 7);
      __builtin_amdgcn_global_load_lds(
        (const __attribute__((address_space(1))) unsigned int*)(A + (size_t)(bm+row)*K + k0 + s*8),
        (__attribute__((address_space(3))) unsigned int*)((char*)As + off), 16, 0, 0);
    }
    if(BF32){
      const float* Bf = (const float*)Bsrc;
      #pragma unroll
      for(int i=0;i<8;i++){
        int kl = (tid>>5) + i*8;
        int nl = (tid&31)*4;
        float4 v = *(const float4*)(Bf + (size_t)(k0+kl)*N + bn + nl);
        int slot = kl >> 3, kb = kl & 7;
        float vv[4] = {v.x, v.y, v.z, v.w};
        #pragma unroll
        for(int jj=0;jj<4;jj++){
          int n = nl + jj;
          Bs[n*64 + ((slot ^ (n&7))*8) + kb] = f2bf(vv[jj]);
        }
      }
    } else {
      const unsigned short* Bt = (const unsigned short*)Bsrc;
      #pragma unroll
      for(int ch=0; ch<4; ch++){
        int off = ch*4096 + tid*16;
        int row = off >> 7;
        int s   = ((off >> 4) & 7) ^ (row & 7);
        __builtin_amdgcn_global_load_lds(
          (const __attribute__((address_space(1))) unsigned int*)(Bt + (size_t)(bn+row)*K + k0 + s*8),
          (__attribute__((address_space(3))) unsigned int*)((char*)Bs + off), 16, 0, 0);
      }
    }
    __syncthreads();

    #pragma unroll
    for(int q=0;q<2;q++){
      s16x8 af[4], bf[4];
      #pragma unroll
      for(int mt=0;mt<4;mt++){
        int row = wm + mt*16 + l15;
        int s = (q*4 + kg) ^ (row & 7);
        af[mt] = *(const s16x8*)(As + row*64 + s*8);
      }
      #pragma unroll
      for(int nt=0;nt<4;nt++){
        int row = wn + nt*16 + l15;
        int s = (q*4 + kg) ^ (row & 7);
        bf[nt] = *(const s16x8*)(Bs + row*64 + s*8);
      }
      #pragma unroll
      for(int mt=0;mt<4;mt++)
        #pragma unroll
        for(int nt=0;nt<4;nt++)
          acc[mt][nt] = __builtin_amdgcn_mfma_f32_16x16x32_bf16(af[mt], bf[nt], acc[mt][nt], 0, 0, 0);
    }
  }
  #pragma unroll
  for(int mt=0;mt<4;mt++){
    #pragma unroll
    for(int nt=0;nt<4;nt++){
      int col = bn + wn + nt*16 + l15;
      float bv = bias ? bias[col] : 0.f;
      #pragma unroll
      for(int e=0;e<4;e++){
        int row = bm + wm + mt*16 + kg*4 + e;
        C[(size_t)row*N + col] = acc[mt][nt][e] + bv;
      }
    }
  }
}

// ------------- persistent 2-layer LSTM, U resident in LDS ------------------
template<int C, int K, int LAYER, int HU>
__device__ __forceinline__ void rnn_body(
    unsigned short* __restrict__ Uld, float* __restrict__ zp,
    const unsigned short* __restrict__ Uslice,
    const float* __restrict__ xw0, const float* __restrict__ bpk,
    const unsigned short* __restrict__ h0init, const unsigned short* __restrict__ h1init,
    const float* __restrict__ cinit,
    unsigned short* __restrict__ h0seq, unsigned short* __restrict__ h1seq,
    float* __restrict__ cfin, unsigned* bar, int cb, unsigned nblk)
{
  constexpr int KW = K/4, KS = KW/32, FR = C/16, UB = C/4;
  constexpr int K2 = K*2;
  constexpr int ITEMS = 16*UB;
  const int tid = threadIdx.x;
  const int lane = tid & 63, w = tid >> 6;
  const int l15 = lane & 15, kg = lane >> 4;

  constexpr int CP = (C*K2)/4096;
  #pragma unroll
  for(int i=0;i<CP;i++){
    __builtin_amdgcn_global_load_lds(
      (const __attribute__((address_space(1))) unsigned int*)((const char*)Uslice + i*4096 + tid*16),
      (__attribute__((address_space(3))) unsigned int*)((char*)Uld + i*4096 + tid*16), 16, 0, 0);
  }
  const int base_p = cb*C;
  const int base_u = cb*UB;
  float4 bvr = make_float4(0.f,0.f,0.f,0.f);
  int er = 0, eu = 0;
  if(tid < ITEMS){ er = tid / UB; eu = tid - er*UB; bvr = *(const float4*)(bpk + base_p + eu*4); }
  float creg = 0.f;
  unsigned short* hseqW = LAYER ? h1seq : h0seq;

  int cbyte[FR], cx[FR];
  #pragma unroll
  for(int f=0;f<FR;f++){ int c = f*16 + l15; cbyte[f] = c*K2; cx[f] = (c&7)<<4; }

  __syncthreads();

  for(int it = 0; it <= T_; ++it){
    const bool active = LAYER ? (it >= 1) : (it < T_);
    const int t = LAYER ? it-1 : it;
    if(active){
      const unsigned short* asrc;
      if constexpr(LAYER == 0){
        asrc = (t == 0) ? (h0init + l15*HU)
                        : (h0seq + ((size_t)(l15*T_ + (t-1)))*HU);
      } else {
        if(w < 2){
          asrc = h0seq + ((size_t)(l15*T_ + t))*HU;
        } else {
          asrc = ((t == 0) ? (h1init + l15*HU)
                           : (h1seq + ((size_t)(l15*T_ + (t-1)))*HU)) - HU;
        }
      }
      f32x4 acc[FR];
      #pragma unroll
      for(int f=0;f<FR;f++) acc[f] = (f32x4){0.f,0.f,0.f,0.f};
      #pragma unroll
      for(int s=0;s<KS;s++){
        const int kel = w*KW + s*32 + kg*8;
        s16x8 a = *(const s16x8*)(asrc + kel);
        const int kb  = kel*2;
        const int kch = kb & ~127;
        const int ksl = (kb >> 4) & 7;
        #pragma unroll
        for(int f=0;f<FR;f++){
          const int ad = cbyte[f] + kch + ((ksl<<4) ^ cx[f]);
          s16x8 b = *(const s16x8*)((const char*)Uld + ad);
          acc[f] = __builtin_amdgcn_mfma_f32_16x16x32_bf16(a, b, acc[f], 0, 0, 0);
        }
      }
      #pragma unroll
      for(int f=0;f<FR;f++)
        #pragma unroll
        for(int e=0;e<4;e++)
          zp[(w*16 + kg*4 + e)*68 + f*16 + l15] = acc[f][e];
    }
    __syncthreads();
    if(active && tid < ITEMS){
      float4 z0 = *(const float4*)(zp + (     er)*68 + eu*4);
      float4 z1 = *(const float4*)(zp + (16 + er)*68 + eu*4);
      float4 z2 = *(const float4*)(zp + (32 + er)*68 + eu*4);
      float4 z3 = *(const float4*)(zp + (48 + er)*68 + eu*4);
      float si = z0.x+z1.x+z2.x+z3.x + bvr.x;
      float sf = z0.y+z1.y+z2.y+z3.y + bvr.y;
      float sg = z0.z+z1.z+z2.z+z3.z + bvr.z;
      float so = z0.w+z1.w+z2.w+z3.w + bvr.w;
      if constexpr(LAYER == 0){
        float4 xv = *(const float4*)(xw0 + ((size_t)(er*T_ + t))*(4*HU) + base_p + eu*4);
        si += xv.x; sf += xv.y; sg += xv.z; so += xv.w;
      }
      float cin = (t == 0) ? cinit[er*HU + base_u + eu] : creg;
      float c2 = sigm(sf)*cin + sigm(si)*tanhf(sg);
      float h2 = sigm(so)*tanhf(c2);
      creg = c2;
      hseqW[((size_t)(er*T_ + t))*HU + base_u + eu] = f2bf(h2);
      if(t == T_-1) cfin[er*HU + base_u + eu] = c2;
    }
    if(it < T_) gbar(bar, nblk);
  }
}

template<int HU, int C0, int C1>
__global__ __launch_bounds__(256, 1)
void k_rnn(const unsigned short* __restrict__ Ut0, const unsigned short* __restrict__ WU1,
           const float* __restrict__ xw0, const float* __restrict__ bpk0, const float* __restrict__ bpk1,
           const unsigned short* __restrict__ h0init, const unsigned short* __restrict__ h1init,
           const float* __restrict__ c0init, const float* __restrict__ c1init,
           unsigned short* __restrict__ h0seq, unsigned short* __restrict__ h1seq,
           float* __restrict__ c0fin, float* __restrict__ c1fin, unsigned* bar)
{
  constexpr int NB0 = 4*HU/C0;
  constexpr int UMAXE = (C0*HU > C1*2*HU) ? C0*HU : C1*2*HU;
  __shared__ __align__(16) unsigned short Uld[UMAXE];
  __shared__ __align__(16) float zred[64*68];
  const unsigned nblk = gridDim.x;
  const int blk = blockIdx.x;
  if(blk < NB0)
    rnn_body<C0, HU, 0, HU>(Uld, zred, Ut0 + (size_t)blk*C0*HU, xw0, bpk0,
                            h0init, h1init, c0init, h0seq, h1seq, c0fin, bar, blk, nblk);
  else
    rnn_body<C1, 2*HU, 1, HU>(Uld, zred, WU1 + (size_t)(blk-NB0)*C1*2*HU, nullptr, bpk1,
                            h0init, h1init, c1init, h0seq, h1seq, c1fin, bar, blk-NB0, nblk);
}

// ---------------------------------------------------------------------------
extern "C" void kernel_launch(void* const* d_in, const int* in_sizes, int n_in,
                              void* d_out, int out_size, void* d_ws, size_t ws_size,
                              hipStream_t stream){
  const int*   ids1 = (const int*)d_in[0];
  const int*   ids2 = (const int*)d_in[1];
  const float* init = (const float*)d_in[2];
  const float* emb  = (const float*)d_in[3];
  const float* W1_0 = (const float*)d_in[4];
  const float* U1_0 = (const float*)d_in[5];
  const float* b1_0 = (const float*)d_in[6];
  const float* W1_1 = (const float*)d_in[7];
  const float* U1_1 = (const float*)d_in[8];
  const float* b1_1 = (const float*)d_in[9];
  const float* W2_0 = (const float*)d_in[10];
  const float* U2_0 = (const float*)d_in[11];
  const float* b2_0 = (const float*)d_in[12];
  const float* W2_1 = (const float*)d_in[13];
  const float* U2_1 = (const float*)d_in[14];
  const float* b2_1 = (const float*)d_in[15];
  const float* Wp1  = (const float*)d_in[16];
  const float* bp1  = (const float*)d_in[17];
  const float* Wp2  = (const float*)d_in[18];
  const float* bp2  = (const float*)d_in[19];
  float* out1 = (float*)d_out;
  float* out2 = out1 + (size_t)B_*T_*V_;

  char* base = (char*)d_ws;
  float*          xw    = (float*)(base);                           // 16 MB
  unsigned short* ut0_1 = (unsigned short*)(base + (16u<<20));      // 2 MB
  unsigned short* wu1_1 = (unsigned short*)(base + (18u<<20));      // 4 MB
  unsigned short* ut0_2 = (unsigned short*)(base + (22u<<20));      // 8 MB
  unsigned short* wu1_2 = (unsigned short*)(base + (30u<<20));      // 16 MB
  unsigned short* wtmp  = (unsigned short*)(base + (46u<<20));      // 4 MB
  unsigned short* ebuf  = (unsigned short*)(base + (50u<<20));      // 1 MB
  unsigned short* h0s1  = (unsigned short*)(base + (51u<<20));      // 1 MB
  unsigned short* h1s1  = (unsigned short*)(base + (52u<<20));      // 1 MB
  unsigned short* h0s2  = (unsigned short*)(base + (53u<<20));      // 2 MB
  unsigned short* h1s2  = (unsigned short*)(base + (55u<<20));      // 2 MB
  char* M = base + (57u<<20);
  unsigned short* h0i1 = (unsigned short*)(M);
  unsigned short* h1i1 = (unsigned short*)(M + 16384);
  float* c0i1 = (float*)(M + 32768);
  float* c1i1 = (float*)(M + 65536);
  unsigned short* h2i0 = (unsigned short*)(M + 98304);
  unsigned short* h2i1 = (unsigned short*)(M + 131072);
  float* c2i0 = (float*)(M + 163840);
  float* c2i1 = (float*)(M + 229376);
  float* c0f1 = (float*)(M + 294912);
  float* c1f1 = (float*)(M + 327680);
  float* c0f2 = (float*)(M + 360448);
  float* c1f2 = (float*)(M + 425984);
  float* bpk10 = (float*)(M + 491520);
  float* bpk11 = (float*)(M + 499712);
  float* bpk20 = (float*)(M + 507904);
  float* bpk21 = (float*)(M + 524288);
  unsigned* bar = (unsigned*)(M + 540672);
  unsigned short* wpT = (unsigned short*)(base + (58u<<20));        // 65.6 MB
  const size_t NEED_ALL = ((size_t)58u<<20) + (size_t)V_*1024*2;
  const bool wide = ws_size >= NEED_ALL;

  k_barinit<<<dim3(1), dim3(1), 0, stream>>>(bar);

  // ================= RNN1 =================
  k_init1<<<dim3(32), dim3(256), 0, stream>>>(init, h0i1, c0i1, h1i1, c1i1);
  k_gather<<<dim3(B_*T_), dim3(128), 0, stream>>>(ids1, emb, ebuf);
  k_tcvt<<<dim3(64, 16), dim3(256), 0, stream>>>(U1_0, ut0_1, 2048, 512, 512, 0, 1);
  k_tcvt<<<dim3(64, 16), dim3(256), 0, stream>>>(W1_0, wtmp,  2048, 512, 512, 0, 0);
  k_tcvt<<<dim3(64, 16), dim3(256), 0, stream>>>(W1_1, wu1_1, 2048, 512, 1024, 0, 1);
  k_tcvt<<<dim3(64, 16), dim3(256), 0, stream>>>(U1_1, wu1_1, 2048, 512, 1024, 512, 1);
  k_bpack<<<dim3(8),  dim3(256), 0, stream>>>(b1_0, bpk10, 512, 2048);
  k_bpack<<<dim3(8),  dim3(256), 0, stream>>>(b1_1, bpk11, 512, 2048);
  k_mm<0><<<dim3(16, 8), dim3(256), 0, stream>>>(ebuf, wtmp, nullptr, xw, 1024, 2048, 512);
  k_rnn<512, 64, 64><<<dim3(64), dim3(256), 0, stream>>>(ut0_1, wu1_1, xw, bpk10, bpk11,
      h0i1, h1i1, c0i1, c1i1, h0s1, h1s1, c0f1, c1f1, bar);
  // projection 1
  if(wide){
    k_tcvt<<<dim3(1000, 16), dim3(256), 0, stream>>>(Wp1, wpT, V_, 0, 512, 0, 0);
    k_mm<0><<<dim3(250, 8), dim3(256), 0, stream>>>(h1s1, wpT, bp1, out1, 1024, V_, 512);
  } else {
    k_mm<1><<<dim3(250, 8), dim3(256), 0, stream>>>(h1s1, Wp1, bp1, out1, 1024, V_, 512);
  }

  // ================= RNN2 =================
  k_init2<<<dim3(64, 2), dim3(256), 0, stream>>>(init, h0s1, h1s1, c0f1, c1f1,
                                                 h2i0, h2i1, c2i0, c2i1);
  k_gather<<<dim3(B_*T_), dim3(128), 0, stream>>>(ids2, emb, ebuf);
  k_tcvt<<<dim3(128, 32), dim3(256), 0, stream>>>(U2_0, ut0_2, 4096, 1024, 1024, 0, 1);
  k_tcvt<<<dim3(128, 16), dim3(256), 0, stream>>>(W2_0, wtmp,  4096, 1024, 512, 0, 0);
  k_tcvt<<<dim3(128, 32), dim3(256), 0, stream>>>(W2_1, wu1_2, 4096, 1024, 2048, 0, 1);
  k_tcvt<<<dim3(128, 32), dim3(256), 0, stream>>>(U2_1, wu1_2, 4096, 1024, 2048, 1024, 1);
  k_bpack<<<dim3(16), dim3(256), 0, stream>>>(b2_0, bpk20, 1024, 4096);
  k_bpack<<<dim3(16), dim3(256), 0, stream>>>(b2_1, bpk21, 1024, 4096);
  k_mm<0><<<dim3(32, 8), dim3(256), 0, stream>>>(ebuf, wtmp, nullptr, xw, 1024, 4096, 512);
  k_rnn<1024, 64, 32><<<dim3(192), dim3(256), 0, stream>>>(ut0_2, wu1_2, xw, bpk20, bpk21,
      h2i0, h2i1, c2i0, c2i1, h0s2, h1s2, c0f2, c1f2, bar);
  // projection 2
  if(wide){
    k_tcvt<<<dim3(1000, 32), dim3(256), 0, stream>>>(Wp2, wpT, V_, 0, 1024, 0, 0);
    k_mm<0><<<dim3(250, 8), dim3(256), 0, stream>>>(h1s2, wpT, bp2, out2, 1024, V_, 1024);
  } else {
    k_mm<1><<<dim3(250, 8), dim3(256), 0, stream>>>(h1s2, Wp2, bp2, out2, 1024, V_, 1024);
  }
}

// Round 6
// 1462.354 us; speedup vs baseline: 4.1241x; 1.4116x over previous
//
#include <hip/hip_runtime.h>
#include <hip/hip_bf16.h>

#define B_ 16
#define T_ 64
#define E_ 512
#define H_ 512
#define V_ 32000

typedef __attribute__((ext_vector_type(4))) float f32x4;
typedef __attribute__((ext_vector_type(8))) short s16x8;

__device__ __forceinline__ float sigm(float x){ return 1.0f/(1.0f + __expf(-x)); }

__device__ __forceinline__ unsigned short f2bf(float x){
  unsigned int u = __float_as_uint(x);
  return (unsigned short)((u + 0x7FFFu + ((u>>16)&1u)) >> 16);
}

// ---- coherence-point ops: no cache-wide writeback/invalidate anywhere ----
__device__ __forceinline__ unsigned load_coh(const unsigned* p){
  unsigned v;
  asm volatile("global_load_dword %0, %1, off sc0 sc1\n\ts_waitcnt vmcnt(0)"
               : "=v"(v) : "v"(p) : "memory");
  return v;
}
__device__ __forceinline__ void store_coh32(unsigned* p, unsigned v){
  asm volatile("global_store_dword %0, %1, off sc0 sc1" :: "v"(p), "v"(v) : "memory");
}
__device__ __forceinline__ void store_coh16(unsigned short* p, unsigned v){
  asm volatile("global_store_short %0, %1, off sc0 sc1" :: "v"(p), "v"(v) : "memory");
}
__device__ __forceinline__ void store_cohf(float* p, float v){
  asm volatile("global_store_dword %0, %1, off sc0 sc1" :: "v"(p), "v"(v) : "memory");
}

// ---- grid barrier: NO wbl2 / NO inv. h-data goes write-through (sc0 sc1),
// so the barrier only needs CP-level arrive + CP-level spin. ----
__device__ __forceinline__ void gbar(unsigned* bar, unsigned nblk){
  asm volatile("s_waitcnt vmcnt(0)" ::: "memory");  // drain this thread's coh stores
  __syncthreads();
  if(threadIdx.x == 0){
    unsigned g = load_coh(bar+1);
    unsigned a = __hip_atomic_fetch_add(bar, 1u, __ATOMIC_RELAXED, __HIP_MEMORY_SCOPE_AGENT);
    if(a == nblk-1u){
      asm volatile("global_store_dword %0, %1, off sc0 sc1\n\ts_waitcnt vmcnt(0)"
                   :: "v"(bar), "v"(0u) : "memory");
      asm volatile("global_store_dword %0, %1, off sc0 sc1\n\ts_waitcnt vmcnt(0)"
                   :: "v"(bar+1), "v"(g+1u) : "memory");
    } else {
      while(load_coh(bar+1) == g) __builtin_amdgcn_s_sleep(1);
    }
  }
  __syncthreads();
}

__global__ void k_barinit(unsigned* bar){ bar[0] = 0u; bar[1] = 0u; }

// ------------- embedding gather -> bf16 [1024][512] ------------------------
__global__ void k_gather(const int* __restrict__ ids, const float* __restrict__ emb,
                         unsigned short* __restrict__ out){
  const int row = blockIdx.x;
  const int id  = ids[row];
  float4 v = *(const float4*)(emb + (size_t)id*E_ + threadIdx.x*4);
  ushort4 o;
  o.x = f2bf(v.x); o.y = f2bf(v.y); o.z = f2bf(v.z); o.w = f2bf(v.w);
  *(ushort4*)(out + (size_t)row*E_ + threadIdx.x*4) = o;
}

// ------------- transpose+convert(+permute)(+swizzle) -----------------------
__global__ __launch_bounds__(256)
void k_tcvt(const float* __restrict__ in, unsigned short* __restrict__ out,
            int N, int Hp, int Kfull, int koff, int swz){
  __shared__ float tile[32][33];
  const int n0 = blockIdx.x*32, k0 = blockIdx.y*32;
  const int x = threadIdx.x & 31, y = threadIdx.x >> 5;
  #pragma unroll
  for(int i=0;i<4;i++){
    int k = y + i*8;
    tile[k][x] = in[(size_t)(k0+k)*N + n0 + x];
  }
  __syncthreads();
  #pragma unroll
  for(int i=0;i<4;i++){
    int nl = y + i*8;
    int n  = n0 + nl;
    int p  = Hp ? ((n % Hp)*4 + n / Hp) : n;
    int kk = koff + k0 + x;
    size_t idx;
    if(swz){
      int k2 = kk*2;
      int slot = ((k2>>4)&7) ^ (p&7);
      idx = (size_t)p*Kfull + (((k2 & ~127) | (slot<<4) | (k2 & 15)) >> 1);
    } else {
      idx = (size_t)p*Kfull + kk;
    }
    out[idx] = f2bf(tile[x][nl]);
  }
}

// ------------- bias permute: bpk[p] = b[(p&3)*H + (p>>2)] -------------------
__global__ void k_bpack(const float* __restrict__ b, float* __restrict__ out, int H, int N){
  int p = blockIdx.x*256 + threadIdx.x;
  if(p < N) out[p] = b[(p&3)*H + (p>>2)];
}

// ------------- init states --------------------------------------------------
__global__ void k_init1(const float* __restrict__ init_state,
                        unsigned short* h0i, float* c0i, unsigned short* h1i, float* c1i){
  int i = blockIdx.x*256 + threadIdx.x;
  if(i >= B_*H_) return;
  float v0 = init_state[i];
  float v1 = init_state[B_*H_ + i];
  h0i[i] = f2bf(v0); c0i[i] = v0;
  h1i[i] = f2bf(v1); c1i[i] = v1;
}

__global__ void k_init2(const float* __restrict__ init_state,
                        const unsigned short* __restrict__ h0seq1,
                        const unsigned short* __restrict__ h1seq1,
                        const float* __restrict__ c0f1, const float* __restrict__ c1f1,
                        unsigned short* h20i, unsigned short* h21i,
                        float* c20i, float* c21i){
  const int l = blockIdx.y;
  int i = blockIdx.x*256 + threadIdx.x;
  if(i >= B_*2*H_) return;
  const int r = i >> 10, j = i & 1023;
  unsigned short* ho = l ? h21i : h20i;
  float* co = l ? c21i : c20i;
  if(j < H_){
    float v = init_state[(size_t)l*B_*H_ + r*H_ + j];
    ho[i] = f2bf(v); co[i] = v;
  } else {
    const unsigned short* hs = l ? h1seq1 : h0seq1;
    const float* cf = l ? c1f1 : c0f1;
    ho[i] = hs[(size_t)(r*T_ + (T_-1))*H_ + (j - H_)];
    co[i] = cf[r*H_ + (j - H_)];
  }
}

// ------------- MFMA GEMM: C[M][N] = A[M][K](bf16) @ B + bias ---------------
template<int BF32>
__global__ __launch_bounds__(256)
void k_mm(const unsigned short* __restrict__ A, const void* __restrict__ Bsrc,
          const float* __restrict__ bias, float* __restrict__ C,
          int M, int N, int K){
  __shared__ __align__(16) unsigned short As[128*64];
  __shared__ __align__(16) unsigned short Bs[128*64];
  const int tid = threadIdx.x;
  const int lane = tid & 63, w = tid >> 6;
  const int wm = (w>>1)*64, wn = (w&1)*64;
  const int bm = blockIdx.y*128, bn = blockIdx.x*128;
  const int l15 = lane & 15, kg = lane >> 4;
  f32x4 acc[4][4] = {};

  for(int k0=0; k0<K; k0+=64){
    __syncthreads();
    #pragma unroll
    for(int ch=0; ch<4; ch++){
      int off = ch*4096 + tid*16;
      int row = off >> 7;
      int s   = ((off >> 4) & 7) ^ (row & 7);
      __builtin_amdgcn_global_load_lds(
        (const __attribute__((address_space(1))) unsigned int*)(A + (size_t)(bm+row)*K + k0 + s*8),
        (__attribute__((address_space(3))) unsigned int*)((char*)As + off), 16, 0, 0);
    }
    if(BF32){
      const float* Bf = (const float*)Bsrc;
      #pragma unroll
      for(int i=0;i<8;i++){
        int kl = (tid>>5) + i*8;
        int nl = (tid&31)*4;
        float4 v = *(const float4*)(Bf + (size_t)(k0+kl)*N + bn + nl);
        int slot = kl >> 3, kb = kl & 7;
        float vv[4] = {v.x, v.y, v.z, v.w};
        #pragma unroll
        for(int jj=0;jj<4;jj++){
          int n = nl + jj;
          Bs[n*64 + ((slot ^ (n&7))*8) + kb] = f2bf(vv[jj]);
        }
      }
    } else {
      const unsigned short* Bt = (const unsigned short*)Bsrc;
      #pragma unroll
      for(int ch=0; ch<4; ch++){
        int off = ch*4096 + tid*16;
        int row = off >> 7;
        int s   = ((off >> 4) & 7) ^ (row & 7);
        __builtin_amdgcn_global_load_lds(
          (const __attribute__((address_space(1))) unsigned int*)(Bt + (size_t)(bn+row)*K + k0 + s*8),
          (__attribute__((address_space(3))) unsigned int*)((char*)Bs + off), 16, 0, 0);
      }
    }
    __syncthreads();

    #pragma unroll
    for(int q=0;q<2;q++){
      s16x8 af[4], bf[4];
      #pragma unroll
      for(int mt=0;mt<4;mt++){
        int row = wm + mt*16 + l15;
        int s = (q*4 + kg) ^ (row & 7);
        af[mt] = *(const s16x8*)(As + row*64 + s*8);
      }
      #pragma unroll
      for(int nt=0;nt<4;nt++){
        int row = wn + nt*16 + l15;
        int s = (q*4 + kg) ^ (row & 7);
        bf[nt] = *(const s16x8*)(Bs + row*64 + s*8);
      }
      #pragma unroll
      for(int mt=0;mt<4;mt++)
        #pragma unroll
        for(int nt=0;nt<4;nt++)
          acc[mt][nt] = __builtin_amdgcn_mfma_f32_16x16x32_bf16(af[mt], bf[nt], acc[mt][nt], 0, 0, 0);
    }
  }
  #pragma unroll
  for(int mt=0;mt<4;mt++){
    #pragma unroll
    for(int nt=0;nt<4;nt++){
      int col = bn + wn + nt*16 + l15;
      float bv = bias ? bias[col] : 0.f;
      #pragma unroll
      for(int e=0;e<4;e++){
        int row = bm + wm + mt*16 + kg*4 + e;
        C[(size_t)row*N + col] = acc[mt][nt][e] + bv;
      }
    }
  }
}

// ------------- persistent 2-layer LSTM, U resident in LDS ------------------
template<int C, int K, int LAYER, int HU>
__device__ __forceinline__ void rnn_body(
    unsigned short* __restrict__ Uld, float* __restrict__ zp,
    const unsigned short* __restrict__ Uslice,
    const float* __restrict__ xw0, const float* __restrict__ bpk,
    const unsigned short* __restrict__ h0init, const unsigned short* __restrict__ h1init,
    const float* __restrict__ cinit,
    unsigned short* __restrict__ h0seq, unsigned short* __restrict__ h1seq,
    float* __restrict__ cfin, unsigned* bar, int cb, unsigned nblk)
{
  constexpr int KW = K/4, KS = KW/32, FR = C/16, UB = C/4;
  constexpr int K2 = K*2;
  constexpr int ITEMS = 16*UB;
  const int tid = threadIdx.x;
  const int lane = tid & 63, w = tid >> 6;
  const int l15 = lane & 15, kg = lane >> 4;

  constexpr int CP = (C*K2)/4096;
  #pragma unroll
  for(int i=0;i<CP;i++){
    __builtin_amdgcn_global_load_lds(
      (const __attribute__((address_space(1))) unsigned int*)((const char*)Uslice + i*4096 + tid*16),
      (__attribute__((address_space(3))) unsigned int*)((char*)Uld + i*4096 + tid*16), 16, 0, 0);
  }
  const int base_p = cb*C;
  const int base_u = cb*UB;
  float4 bvr = make_float4(0.f,0.f,0.f,0.f);
  int er = 0, eu = 0;
  if(tid < ITEMS){ er = tid / UB; eu = tid - er*UB; bvr = *(const float4*)(bpk + base_p + eu*4); }
  float creg = 0.f;
  unsigned short* hseqW = LAYER ? h1seq : h0seq;

  int cbyte[FR], cx[FR];
  #pragma unroll
  for(int f=0;f<FR;f++){ int c = f*16 + l15; cbyte[f] = c*K2; cx[f] = (c&7)<<4; }

  __syncthreads();

  for(int it = 0; it <= T_; ++it){
    const bool active = LAYER ? (it >= 1) : (it < T_);
    const int t = LAYER ? it-1 : it;
    if(active){
      const unsigned short* asrc;
      if constexpr(LAYER == 0){
        asrc = (t == 0) ? (h0init + l15*HU)
                        : (h0seq + ((size_t)(l15*T_ + (t-1)))*HU);
      } else {
        if(w < 2){
          asrc = h0seq + ((size_t)(l15*T_ + t))*HU;
        } else {
          asrc = ((t == 0) ? (h1init + l15*HU)
                           : (h1seq + ((size_t)(l15*T_ + (t-1)))*HU)) - HU;
        }
      }
      f32x4 acc[FR];
      #pragma unroll
      for(int f=0;f<FR;f++) acc[f] = (f32x4){0.f,0.f,0.f,0.f};
      #pragma unroll
      for(int s=0;s<KS;s++){
        const int kel = w*KW + s*32 + kg*8;
        s16x8 a = *(const s16x8*)(asrc + kel);
        const int kb  = kel*2;
        const int kch = kb & ~127;
        const int ksl = (kb >> 4) & 7;
        #pragma unroll
        for(int f=0;f<FR;f++){
          const int ad = cbyte[f] + kch + ((ksl<<4) ^ cx[f]);
          s16x8 b = *(const s16x8*)((const char*)Uld + ad);
          acc[f] = __builtin_amdgcn_mfma_f32_16x16x32_bf16(a, b, acc[f], 0, 0, 0);
        }
      }
      #pragma unroll
      for(int f=0;f<FR;f++)
        #pragma unroll
        for(int e=0;e<4;e++)
          zp[(w*16 + kg*4 + e)*68 + f*16 + l15] = acc[f][e];
    }
    __syncthreads();
    if(active && tid < ITEMS){
      float4 z0 = *(const float4*)(zp + (     er)*68 + eu*4);
      float4 z1 = *(const float4*)(zp + (16 + er)*68 + eu*4);
      float4 z2 = *(const float4*)(zp + (32 + er)*68 + eu*4);
      float4 z3 = *(const float4*)(zp + (48 + er)*68 + eu*4);
      float si = z0.x+z1.x+z2.x+z3.x + bvr.x;
      float sf = z0.y+z1.y+z2.y+z3.y + bvr.y;
      float sg = z0.z+z1.z+z2.z+z3.z + bvr.z;
      float so = z0.w+z1.w+z2.w+z3.w + bvr.w;
      if constexpr(LAYER == 0){
        float4 xv = *(const float4*)(xw0 + ((size_t)(er*T_ + t))*(4*HU) + base_p + eu*4);
        si += xv.x; sf += xv.y; sg += xv.z; so += xv.w;
      }
      float cin = (t == 0) ? cinit[er*HU + base_u + eu] : creg;
      float c2 = sigm(sf)*cin + sigm(si)*tanhf(sg);
      float h2 = sigm(so)*tanhf(c2);
      creg = c2;
      // write-through to coherence point: keeps the grid barrier free of
      // any cache-wide writeback/invalidate (lines are written once, read after)
      store_coh16(&hseqW[((size_t)(er*T_ + t))*HU + base_u + eu], (unsigned)f2bf(h2));
      if(t == T_-1) store_cohf(&cfin[er*HU + base_u + eu], c2);
    }
    if(it < T_) gbar(bar, nblk);
  }
}

template<int HU, int C0, int C1>
__global__ __launch_bounds__(256, 1)
void k_rnn(const unsigned short* __restrict__ Ut0, const unsigned short* __restrict__ WU1,
           const float* __restrict__ xw0, const float* __restrict__ bpk0, const float* __restrict__ bpk1,
           const unsigned short* __restrict__ h0init, const unsigned short* __restrict__ h1init,
           const float* __restrict__ c0init, const float* __restrict__ c1init,
           unsigned short* __restrict__ h0seq, unsigned short* __restrict__ h1seq,
           float* __restrict__ c0fin, float* __restrict__ c1fin, unsigned* bar)
{
  constexpr int NB0 = 4*HU/C0;
  constexpr int UMAXE = (C0*HU > C1*2*HU) ? C0*HU : C1*2*HU;
  __shared__ __align__(16) unsigned short Uld[UMAXE];
  __shared__ __align__(16) float zred[64*68];
  const unsigned nblk = gridDim.x;
  const int blk = blockIdx.x;
  if(blk < NB0)
    rnn_body<C0, HU, 0, HU>(Uld, zred, Ut0 + (size_t)blk*C0*HU, xw0, bpk0,
                            h0init, h1init, c0init, h0seq, h1seq, c0fin, bar, blk, nblk);
  else
    rnn_body<C1, 2*HU, 1, HU>(Uld, zred, WU1 + (size_t)(blk-NB0)*C1*2*HU, nullptr, bpk1,
                            h0init, h1init, c1init, h0seq, h1seq, c1fin, bar, blk-NB0, nblk);
}

// ---------------------------------------------------------------------------
extern "C" void kernel_launch(void* const* d_in, const int* in_sizes, int n_in,
                              void* d_out, int out_size, void* d_ws, size_t ws_size,
                              hipStream_t stream){
  const int*   ids1 = (const int*)d_in[0];
  const int*   ids2 = (const int*)d_in[1];
  const float* init = (const float*)d_in[2];
  const float* emb  = (const float*)d_in[3];
  const float* W1_0 = (const float*)d_in[4];
  const float* U1_0 = (const float*)d_in[5];
  const float* b1_0 = (const float*)d_in[6];
  const float* W1_1 = (const float*)d_in[7];
  const float* U1_1 = (const float*)d_in[8];
  const float* b1_1 = (const float*)d_in[9];
  const float* W2_0 = (const float*)d_in[10];
  const float* U2_0 = (const float*)d_in[11];
  const float* b2_0 = (const float*)d_in[12];
  const float* W2_1 = (const float*)d_in[13];
  const float* U2_1 = (const float*)d_in[14];
  const float* b2_1 = (const float*)d_in[15];
  const float* Wp1  = (const float*)d_in[16];
  const float* bp1  = (const float*)d_in[17];
  const float* Wp2  = (const float*)d_in[18];
  const float* bp2  = (const float*)d_in[19];
  float* out1 = (float*)d_out;
  float* out2 = out1 + (size_t)B_*T_*V_;

  char* base = (char*)d_ws;
  float*          xw    = (float*)(base);                           // 16 MB
  unsigned short* ut0_1 = (unsigned short*)(base + (16u<<20));      // 2 MB
  unsigned short* wu1_1 = (unsigned short*)(base + (18u<<20));      // 4 MB
  unsigned short* ut0_2 = (unsigned short*)(base + (22u<<20));      // 8 MB
  unsigned short* wu1_2 = (unsigned short*)(base + (30u<<20));      // 16 MB
  unsigned short* wtmp  = (unsigned short*)(base + (46u<<20));      // 4 MB
  unsigned short* ebuf  = (unsigned short*)(base + (50u<<20));      // 1 MB
  unsigned short* h0s1  = (unsigned short*)(base + (51u<<20));      // 1 MB
  unsigned short* h1s1  = (unsigned short*)(base + (52u<<20));      // 1 MB
  unsigned short* h0s2  = (unsigned short*)(base + (53u<<20));      // 2 MB
  unsigned short* h1s2  = (unsigned short*)(base + (55u<<20));      // 2 MB
  char* M = base + (57u<<20);
  unsigned short* h0i1 = (unsigned short*)(M);
  unsigned short* h1i1 = (unsigned short*)(M + 16384);
  float* c0i1 = (float*)(M + 32768);
  float* c1i1 = (float*)(M + 65536);
  unsigned short* h2i0 = (unsigned short*)(M + 98304);
  unsigned short* h2i1 = (unsigned short*)(M + 131072);
  float* c2i0 = (float*)(M + 163840);
  float* c2i1 = (float*)(M + 229376);
  float* c0f1 = (float*)(M + 294912);
  float* c1f1 = (float*)(M + 327680);
  float* c0f2 = (float*)(M + 360448);
  float* c1f2 = (float*)(M + 425984);
  float* bpk10 = (float*)(M + 491520);
  float* bpk11 = (float*)(M + 499712);
  float* bpk20 = (float*)(M + 507904);
  float* bpk21 = (float*)(M + 524288);
  unsigned* bar = (unsigned*)(M + 540672);
  unsigned short* wpT = (unsigned short*)(base + (58u<<20));        // 65.6 MB
  const size_t NEED_ALL = ((size_t)58u<<20) + (size_t)V_*1024*2;
  const bool wide = ws_size >= NEED_ALL;

  k_barinit<<<dim3(1), dim3(1), 0, stream>>>(bar);

  // ================= RNN1 =================
  k_init1<<<dim3(32), dim3(256), 0, stream>>>(init, h0i1, c0i1, h1i1, c1i1);
  k_gather<<<dim3(B_*T_), dim3(128), 0, stream>>>(ids1, emb, ebuf);
  k_tcvt<<<dim3(64, 16), dim3(256), 0, stream>>>(U1_0, ut0_1, 2048, 512, 512, 0, 1);
  k_tcvt<<<dim3(64, 16), dim3(256), 0, stream>>>(W1_0, wtmp,  2048, 512, 512, 0, 0);
  k_tcvt<<<dim3(64, 16), dim3(256), 0, stream>>>(W1_1, wu1_1, 2048, 512, 1024, 0, 1);
  k_tcvt<<<dim3(64, 16), dim3(256), 0, stream>>>(U1_1, wu1_1, 2048, 512, 1024, 512, 1);
  k_bpack<<<dim3(8),  dim3(256), 0, stream>>>(b1_0, bpk10, 512, 2048);
  k_bpack<<<dim3(8),  dim3(256), 0, stream>>>(b1_1, bpk11, 512, 2048);
  k_mm<0><<<dim3(16, 8), dim3(256), 0, stream>>>(ebuf, wtmp, nullptr, xw, 1024, 2048, 512);
  k_rnn<512, 64, 64><<<dim3(64), dim3(256), 0, stream>>>(ut0_1, wu1_1, xw, bpk10, bpk11,
      h0i1, h1i1, c0i1, c1i1, h0s1, h1s1, c0f1, c1f1, bar);
  // projection 1
  if(wide){
    k_tcvt<<<dim3(1000, 16), dim3(256), 0, stream>>>(Wp1, wpT, V_, 0, 512, 0, 0);
    k_mm<0><<<dim3(250, 8), dim3(256), 0, stream>>>(h1s1, wpT, bp1, out1, 1024, V_, 512);
  } else {
    k_mm<1><<<dim3(250, 8), dim3(256), 0, stream>>>(h1s1, Wp1, bp1, out1, 1024, V_, 512);
  }

  // ================= RNN2 =================
  k_init2<<<dim3(64, 2), dim3(256), 0, stream>>>(init, h0s1, h1s1, c0f1, c1f1,
                                                 h2i0, h2i1, c2i0, c2i1);
  k_gather<<<dim3(B_*T_), dim3(128), 0, stream>>>(ids2, emb, ebuf);
  k_tcvt<<<dim3(128, 32), dim3(256), 0, stream>>>(U2_0, ut0_2, 4096, 1024, 1024, 0, 1);
  k_tcvt<<<dim3(128, 16), dim3(256), 0, stream>>>(W2_0, wtmp,  4096, 1024, 512, 0, 0);
  k_tcvt<<<dim3(128, 32), dim3(256), 0, stream>>>(W2_1, wu1_2, 4096, 1024, 2048, 0, 1);
  k_tcvt<<<dim3(128, 32), dim3(256), 0, stream>>>(U2_1, wu1_2, 4096, 1024, 2048, 1024, 1);
  k_bpack<<<dim3(16), dim3(256), 0, stream>>>(b2_0, bpk20, 1024, 4096);
  k_bpack<<<dim3(16), dim3(256), 0, stream>>>(b2_1, bpk21, 1024, 4096);
  k_mm<0><<<dim3(32, 8), dim3(256), 0, stream>>>(ebuf, wtmp, nullptr, xw, 1024, 4096, 512);
  k_rnn<1024, 64, 32><<<dim3(192), dim3(256), 0, stream>>>(ut0_2, wu1_2, xw, bpk20, bpk21,
      h2i0, h2i1, c2i0, c2i1, h0s2, h1s2, c0f2, c1f2, bar);
  // projection 2
  if(wide){
    k_tcvt<<<dim3(1000, 32), dim3(256), 0, stream>>>(Wp2, wpT, V_, 0, 1024, 0, 0);
    k_mm<0><<<dim3(250, 8), dim3(256), 0, stream>>>(h1s2, wpT, bp2, out2, 1024, V_, 1024);
  } else {
    k_mm<1><<<dim3(250, 8), dim3(256), 0, stream>>>(h1s2, Wp2, bp2, out2, 1024, V_, 1024);
  }
}

// Round 7
// 934.307 us; speedup vs baseline: 6.4549x; 1.5652x over previous
//
#include <hip/hip_runtime.h>
#include <hip/hip_bf16.h>

#define B_ 16
#define T_ 64
#define E_ 512
#define H_ 512
#define V_ 32000

typedef __attribute__((ext_vector_type(4))) float f32x4;
typedef __attribute__((ext_vector_type(8))) short s16x8;

__device__ __forceinline__ float sigm(float x){ return 1.0f/(1.0f + __expf(-x)); }

__device__ __forceinline__ unsigned short f2bf(float x){
  unsigned int u = __float_as_uint(x);
  return (unsigned short)((u + 0x7FFFu + ((u>>16)&1u)) >> 16);
}

// ---- coherence-point ops: no cache-wide writeback/invalidate anywhere ----
__device__ __forceinline__ unsigned load_coh(const unsigned* p){
  unsigned v;
  asm volatile("global_load_dword %0, %1, off sc0 sc1\n\ts_waitcnt vmcnt(0)"
               : "=v"(v) : "v"(p) : "memory");
  return v;
}
__device__ __forceinline__ void store_coh16(unsigned short* p, unsigned v){
  asm volatile("global_store_short %0, %1, off sc0 sc1" :: "v"(p), "v"(v) : "memory");
}
__device__ __forceinline__ void store_cohf(float* p, float v){
  asm volatile("global_store_dword %0, %1, off sc0 sc1" :: "v"(p), "v"(v) : "memory");
}

// ---- distributed monotone grid barrier -----------------------------------
// 8 arrival counters on separate 256B lines (parallel CP channels) + master
// + gen. No resets: at barrier bi (1-based), last-in-group sees
// a == bi*grpcnt-1, last group sees m == bi*8-1, bumps gen=bi (coh store).
__device__ __forceinline__ void gbar2(unsigned* barb, unsigned bi1,
                                      unsigned grp, unsigned grpcnt){
  asm volatile("s_waitcnt vmcnt(0)" ::: "memory");  // drain coh h-stores
  __syncthreads();
  if(threadIdx.x == 0){
    unsigned* ctr = barb + (size_t)grp*64;
    unsigned* mst = barb + (size_t)8*64;
    unsigned* gen = barb + (size_t)9*64;
    unsigned a = __hip_atomic_fetch_add(ctr, 1u, __ATOMIC_RELAXED, __HIP_MEMORY_SCOPE_AGENT);
    if(a == bi1*grpcnt - 1u){
      unsigned m = __hip_atomic_fetch_add(mst, 1u, __ATOMIC_RELAXED, __HIP_MEMORY_SCOPE_AGENT);
      if(m == bi1*8u - 1u){
        asm volatile("global_store_dword %0, %1, off sc0 sc1\n\ts_waitcnt vmcnt(0)"
                     :: "v"(gen), "v"(bi1) : "memory");
      }
    }
    while(load_coh(gen) < bi1) __builtin_amdgcn_s_sleep(1);
  }
  __syncthreads();
}

__global__ void k_barinit(unsigned* bar){
  int i = blockIdx.x*256 + threadIdx.x;
  if(i < 2048) bar[i] = 0u;     // two 4KB regions
}

// ------------- embedding gather -> bf16 [1024][512] ------------------------
__global__ void k_gather(const int* __restrict__ ids, const float* __restrict__ emb,
                         unsigned short* __restrict__ out){
  const int row = blockIdx.x;
  const int id  = ids[row];
  float4 v = *(const float4*)(emb + (size_t)id*E_ + threadIdx.x*4);
  ushort4 o;
  o.x = f2bf(v.x); o.y = f2bf(v.y); o.z = f2bf(v.z); o.w = f2bf(v.w);
  *(ushort4*)(out + (size_t)row*E_ + threadIdx.x*4) = o;
}

// ------------- transpose+convert(+permute)(+swizzle) -----------------------
__global__ __launch_bounds__(256)
void k_tcvt(const float* __restrict__ in, unsigned short* __restrict__ out,
            int N, int Hp, int Kfull, int koff, int swz){
  __shared__ float tile[32][33];
  const int n0 = blockIdx.x*32, k0 = blockIdx.y*32;
  const int x = threadIdx.x & 31, y = threadIdx.x >> 5;
  #pragma unroll
  for(int i=0;i<4;i++){
    int k = y + i*8;
    tile[k][x] = in[(size_t)(k0+k)*N + n0 + x];
  }
  __syncthreads();
  #pragma unroll
  for(int i=0;i<4;i++){
    int nl = y + i*8;
    int n  = n0 + nl;
    int p  = Hp ? ((n % Hp)*4 + n / Hp) : n;
    int kk = koff + k0 + x;
    size_t idx;
    if(swz){
      int k2 = kk*2;
      int slot = ((k2>>4)&7) ^ (p&7);
      idx = (size_t)p*Kfull + (((k2 & ~127) | (slot<<4) | (k2 & 15)) >> 1);
    } else {
      idx = (size_t)p*Kfull + kk;
    }
    out[idx] = f2bf(tile[x][nl]);
  }
}

// ------------- bias permute: bpk[p] = b[(p&3)*H + (p>>2)] -------------------
__global__ void k_bpack(const float* __restrict__ b, float* __restrict__ out, int H, int N){
  int p = blockIdx.x*256 + threadIdx.x;
  if(p < N) out[p] = b[(p&3)*H + (p>>2)];
}

// ------------- init states --------------------------------------------------
__global__ void k_init1(const float* __restrict__ init_state,
                        unsigned short* h0i, float* c0i, unsigned short* h1i, float* c1i){
  int i = blockIdx.x*256 + threadIdx.x;
  if(i >= B_*H_) return;
  float v0 = init_state[i];
  float v1 = init_state[B_*H_ + i];
  h0i[i] = f2bf(v0); c0i[i] = v0;
  h1i[i] = f2bf(v1); c1i[i] = v1;
}

__global__ void k_init2(const float* __restrict__ init_state,
                        const unsigned short* __restrict__ h0seq1,
                        const unsigned short* __restrict__ h1seq1,
                        const float* __restrict__ c0f1, const float* __restrict__ c1f1,
                        unsigned short* h20i, unsigned short* h21i,
                        float* c20i, float* c21i){
  const int l = blockIdx.y;
  int i = blockIdx.x*256 + threadIdx.x;
  if(i >= B_*2*H_) return;
  const int r = i >> 10, j = i & 1023;
  unsigned short* ho = l ? h21i : h20i;
  float* co = l ? c21i : c20i;
  if(j < H_){
    float v = init_state[(size_t)l*B_*H_ + r*H_ + j];
    ho[i] = f2bf(v); co[i] = v;
  } else {
    const unsigned short* hs = l ? h1seq1 : h0seq1;
    const float* cf = l ? c1f1 : c0f1;
    ho[i] = hs[(size_t)(r*T_ + (T_-1))*H_ + (j - H_)];
    co[i] = cf[r*H_ + (j - H_)];
  }
}

// ------------- MFMA GEMM: C[M][N] = A[M][K](bf16) @ B + bias ---------------
template<int BF32>
__global__ __launch_bounds__(256)
void k_mm(const unsigned short* __restrict__ A, const void* __restrict__ Bsrc,
          const float* __restrict__ bias, float* __restrict__ C,
          int M, int N, int K){
  __shared__ __align__(16) unsigned short As[128*64];
  __shared__ __align__(16) unsigned short Bs[128*64];
  const int tid = threadIdx.x;
  const int lane = tid & 63, w = tid >> 6;
  const int wm = (w>>1)*64, wn = (w&1)*64;
  const int bm = blockIdx.y*128, bn = blockIdx.x*128;
  const int l15 = lane & 15, kg = lane >> 4;
  f32x4 acc[4][4] = {};

  for(int k0=0; k0<K; k0+=64){
    __syncthreads();
    #pragma unroll
    for(int ch=0; ch<4; ch++){
      int off = ch*4096 + tid*16;
      int row = off >> 7;
      int s   = ((off >> 4) & 7) ^ (row & 7);
      __builtin_amdgcn_global_load_lds(
        (const __attribute__((address_space(1))) unsigned int*)(A + (size_t)(bm+row)*K + k0 + s*8),
        (__attribute__((address_space(3))) unsigned int*)((char*)As + off), 16, 0, 0);
    }
    if(BF32){
      const float* Bf = (const float*)Bsrc;
      #pragma unroll
      for(int i=0;i<8;i++){
        int kl = (tid>>5) + i*8;
        int nl = (tid&31)*4;
        float4 v = *(const float4*)(Bf + (size_t)(k0+kl)*N + bn + nl);
        int slot = kl >> 3, kb = kl & 7;
        float vv[4] = {v.x, v.y, v.z, v.w};
        #pragma unroll
        for(int jj=0;jj<4;jj++){
          int n = nl + jj;
          Bs[n*64 + ((slot ^ (n&7))*8) + kb] = f2bf(vv[jj]);
        }
      }
    } else {
      const unsigned short* Bt = (const unsigned short*)Bsrc;
      #pragma unroll
      for(int ch=0; ch<4; ch++){
        int off = ch*4096 + tid*16;
        int row = off >> 7;
        int s   = ((off >> 4) & 7) ^ (row & 7);
        __builtin_amdgcn_global_load_lds(
          (const __attribute__((address_space(1))) unsigned int*)(Bt + (size_t)(bn+row)*K + k0 + s*8),
          (__attribute__((address_space(3))) unsigned int*)((char*)Bs + off), 16, 0, 0);
      }
    }
    __syncthreads();

    #pragma unroll
    for(int q=0;q<2;q++){
      s16x8 af[4], bf[4];
      #pragma unroll
      for(int mt=0;mt<4;mt++){
        int row = wm + mt*16 + l15;
        int s = (q*4 + kg) ^ (row & 7);
        af[mt] = *(const s16x8*)(As + row*64 + s*8);
      }
      #pragma unroll
      for(int nt=0;nt<4;nt++){
        int row = wn + nt*16 + l15;
        int s = (q*4 + kg) ^ (row & 7);
        bf[nt] = *(const s16x8*)(Bs + row*64 + s*8);
      }
      #pragma unroll
      for(int mt=0;mt<4;mt++)
        #pragma unroll
        for(int nt=0;nt<4;nt++)
          acc[mt][nt] = __builtin_amdgcn_mfma_f32_16x16x32_bf16(af[mt], bf[nt], acc[mt][nt], 0, 0, 0);
    }
  }
  #pragma unroll
  for(int mt=0;mt<4;mt++){
    #pragma unroll
    for(int nt=0;nt<4;nt++){
      int col = bn + wn + nt*16 + l15;
      float bv = bias ? bias[col] : 0.f;
      #pragma unroll
      for(int e=0;e<4;e++){
        int row = bm + wm + mt*16 + kg*4 + e;
        C[(size_t)row*N + col] = acc[mt][nt][e] + bv;
      }
    }
  }
}

// ------------- persistent 2-layer LSTM, U resident in LDS ------------------
template<int C, int K, int LAYER, int HU>
__device__ __forceinline__ void rnn_body(
    unsigned short* __restrict__ Uld, float* __restrict__ zp,
    const unsigned short* __restrict__ Uslice,
    const float* __restrict__ xw0, const float* __restrict__ bpk,
    const unsigned short* __restrict__ h0init, const unsigned short* __restrict__ h1init,
    const float* __restrict__ cinit,
    unsigned short* __restrict__ h0seq, unsigned short* __restrict__ h1seq,
    float* __restrict__ cfin, unsigned* bar, int cb,
    unsigned grp, unsigned grpcnt)
{
  constexpr int KW = K/4, KS = KW/32, FR = C/16, UB = C/4;
  constexpr int K2 = K*2;
  constexpr int ITEMS = 16*UB;
  const int tid = threadIdx.x;
  const int lane = tid & 63, w = tid >> 6;
  const int l15 = lane & 15, kg = lane >> 4;

  constexpr int CP = (C*K2)/4096;
  #pragma unroll
  for(int i=0;i<CP;i++){
    __builtin_amdgcn_global_load_lds(
      (const __attribute__((address_space(1))) unsigned int*)((const char*)Uslice + i*4096 + tid*16),
      (__attribute__((address_space(3))) unsigned int*)((char*)Uld + i*4096 + tid*16), 16, 0, 0);
  }
  const int base_p = cb*C;
  const int base_u = cb*UB;
  float4 bvr = make_float4(0.f,0.f,0.f,0.f);
  int er = 0, eu = 0;
  if(tid < ITEMS){ er = tid / UB; eu = tid - er*UB; bvr = *(const float4*)(bpk + base_p + eu*4); }
  float creg = 0.f;
  unsigned short* hseqW = LAYER ? h1seq : h0seq;

  int cbyte[FR], cx[FR];
  #pragma unroll
  for(int f=0;f<FR;f++){ int c = f*16 + l15; cbyte[f] = c*K2; cx[f] = (c&7)<<4; }

  __syncthreads();

  for(int it = 0; it <= T_; ++it){
    const bool active = LAYER ? (it >= 1) : (it < T_);
    const int t = LAYER ? it-1 : it;
    if(active){
      const unsigned short* asrc;
      if constexpr(LAYER == 0){
        asrc = (t == 0) ? (h0init + l15*HU)
                        : (h0seq + ((size_t)(l15*T_ + (t-1)))*HU);
      } else {
        if(w < 2){
          asrc = h0seq + ((size_t)(l15*T_ + t))*HU;
        } else {
          asrc = ((t == 0) ? (h1init + l15*HU)
                           : (h1seq + ((size_t)(l15*T_ + (t-1)))*HU)) - HU;
        }
      }
      f32x4 acc[FR];
      #pragma unroll
      for(int f=0;f<FR;f++) acc[f] = (f32x4){0.f,0.f,0.f,0.f};
      #pragma unroll
      for(int s=0;s<KS;s++){
        const int kel = w*KW + s*32 + kg*8;
        s16x8 a = *(const s16x8*)(asrc + kel);
        const int kb  = kel*2;
        const int kch = kb & ~127;
        const int ksl = (kb >> 4) & 7;
        #pragma unroll
        for(int f=0;f<FR;f++){
          const int ad = cbyte[f] + kch + ((ksl<<4) ^ cx[f]);
          s16x8 b = *(const s16x8*)((const char*)Uld + ad);
          acc[f] = __builtin_amdgcn_mfma_f32_16x16x32_bf16(a, b, acc[f], 0, 0, 0);
        }
      }
      #pragma unroll
      for(int f=0;f<FR;f++)
        #pragma unroll
        for(int e=0;e<4;e++)
          zp[(w*16 + kg*4 + e)*68 + f*16 + l15] = acc[f][e];
    }
    __syncthreads();
    if(active && tid < ITEMS){
      float4 z0 = *(const float4*)(zp + (     er)*68 + eu*4);
      float4 z1 = *(const float4*)(zp + (16 + er)*68 + eu*4);
      float4 z2 = *(const float4*)(zp + (32 + er)*68 + eu*4);
      float4 z3 = *(const float4*)(zp + (48 + er)*68 + eu*4);
      float si = z0.x+z1.x+z2.x+z3.x + bvr.x;
      float sf = z0.y+z1.y+z2.y+z3.y + bvr.y;
      float sg = z0.z+z1.z+z2.z+z3.z + bvr.z;
      float so = z0.w+z1.w+z2.w+z3.w + bvr.w;
      if constexpr(LAYER == 0){
        float4 xv = *(const float4*)(xw0 + ((size_t)(er*T_ + t))*(4*HU) + base_p + eu*4);
        si += xv.x; sf += xv.y; sg += xv.z; so += xv.w;
      }
      float cin = (t == 0) ? cinit[er*HU + base_u + eu] : creg;
      float c2 = sigm(sf)*cin + sigm(si)*tanhf(sg);
      float h2 = sigm(so)*tanhf(c2);
      creg = c2;
      store_coh16(&hseqW[((size_t)(er*T_ + t))*HU + base_u + eu], (unsigned)f2bf(h2));
      if(t == T_-1) store_cohf(&cfin[er*HU + base_u + eu], c2);
    }
    if(it < T_) gbar2(bar, (unsigned)(it+1), grp, grpcnt);
  }
}

template<int HU, int C0, int C1>
__global__ __launch_bounds__(256, 1)
void k_rnn(const unsigned short* __restrict__ Ut0, const unsigned short* __restrict__ WU1,
           const float* __restrict__ xw0, const float* __restrict__ bpk0, const float* __restrict__ bpk1,
           const unsigned short* __restrict__ h0init, const unsigned short* __restrict__ h1init,
           const float* __restrict__ c0init, const float* __restrict__ c1init,
           unsigned short* __restrict__ h0seq, unsigned short* __restrict__ h1seq,
           float* __restrict__ c0fin, float* __restrict__ c1fin, unsigned* bar)
{
  constexpr int NB0 = 4*HU/C0;
  constexpr int UMAXE = (C0*HU > C1*2*HU) ? C0*HU : C1*2*HU;
  __shared__ __align__(16) unsigned short Uld[UMAXE];
  __shared__ __align__(16) float zred[64*68];
  const unsigned grp = blockIdx.x & 7u;
  const unsigned grpcnt = gridDim.x >> 3;
  const int blk = blockIdx.x;
  if(blk < NB0)
    rnn_body<C0, HU, 0, HU>(Uld, zred, Ut0 + (size_t)blk*C0*HU, xw0, bpk0,
                            h0init, h1init, c0init, h0seq, h1seq, c0fin, bar, blk, grp, grpcnt);
  else
    rnn_body<C1, 2*HU, 1, HU>(Uld, zred, WU1 + (size_t)(blk-NB0)*C1*2*HU, nullptr, bpk1,
                            h0init, h1init, c1init, h0seq, h1seq, c1fin, bar, blk-NB0, grp, grpcnt);
}

// ---------------------------------------------------------------------------
extern "C" void kernel_launch(void* const* d_in, const int* in_sizes, int n_in,
                              void* d_out, int out_size, void* d_ws, size_t ws_size,
                              hipStream_t stream){
  const int*   ids1 = (const int*)d_in[0];
  const int*   ids2 = (const int*)d_in[1];
  const float* init = (const float*)d_in[2];
  const float* emb  = (const float*)d_in[3];
  const float* W1_0 = (const float*)d_in[4];
  const float* U1_0 = (const float*)d_in[5];
  const float* b1_0 = (const float*)d_in[6];
  const float* W1_1 = (const float*)d_in[7];
  const float* U1_1 = (const float*)d_in[8];
  const float* b1_1 = (const float*)d_in[9];
  const float* W2_0 = (const float*)d_in[10];
  const float* U2_0 = (const float*)d_in[11];
  const float* b2_0 = (const float*)d_in[12];
  const float* W2_1 = (const float*)d_in[13];
  const float* U2_1 = (const float*)d_in[14];
  const float* b2_1 = (const float*)d_in[15];
  const float* Wp1  = (const float*)d_in[16];
  const float* bp1  = (const float*)d_in[17];
  const float* Wp2  = (const float*)d_in[18];
  const float* bp2  = (const float*)d_in[19];
  float* out1 = (float*)d_out;
  float* out2 = out1 + (size_t)B_*T_*V_;

  char* base = (char*)d_ws;
  float*          xw    = (float*)(base);                           // 16 MB
  unsigned short* ut0_1 = (unsigned short*)(base + (16u<<20));      // 2 MB
  unsigned short* wu1_1 = (unsigned short*)(base + (18u<<20));      // 4 MB
  unsigned short* ut0_2 = (unsigned short*)(base + (22u<<20));      // 8 MB
  unsigned short* wu1_2 = (unsigned short*)(base + (30u<<20));      // 16 MB
  unsigned short* wtmp  = (unsigned short*)(base + (46u<<20));      // 4 MB
  unsigned short* ebuf  = (unsigned short*)(base + (50u<<20));      // 1 MB
  unsigned short* h0s1  = (unsigned short*)(base + (51u<<20));      // 1 MB
  unsigned short* h1s1  = (unsigned short*)(base + (52u<<20));      // 1 MB
  unsigned short* h0s2  = (unsigned short*)(base + (53u<<20));      // 2 MB
  unsigned short* h1s2  = (unsigned short*)(base + (55u<<20));      // 2 MB
  char* M = base + (57u<<20);
  unsigned short* h0i1 = (unsigned short*)(M);
  unsigned short* h1i1 = (unsigned short*)(M + 16384);
  float* c0i1 = (float*)(M + 32768);
  float* c1i1 = (float*)(M + 65536);
  unsigned short* h2i0 = (unsigned short*)(M + 98304);
  unsigned short* h2i1 = (unsigned short*)(M + 131072);
  float* c2i0 = (float*)(M + 163840);
  float* c2i1 = (float*)(M + 229376);
  float* c0f1 = (float*)(M + 294912);
  float* c1f1 = (float*)(M + 327680);
  float* c0f2 = (float*)(M + 360448);
  float* c1f2 = (float*)(M + 425984);
  float* bpk10 = (float*)(M + 491520);
  float* bpk11 = (float*)(M + 499712);
  float* bpk20 = (float*)(M + 507904);
  float* bpk21 = (float*)(M + 524288);
  unsigned* bar1 = (unsigned*)(M + 540672);        // 4 KB
  unsigned* bar2 = (unsigned*)(M + 544768);        // 4 KB
  unsigned short* wpT = (unsigned short*)(base + (58u<<20));        // 65.6 MB
  const size_t NEED_ALL = ((size_t)58u<<20) + (size_t)V_*1024*2;
  const bool wide = ws_size >= NEED_ALL;

  k_barinit<<<dim3(8), dim3(256), 0, stream>>>(bar1);

  // ================= RNN1 =================
  k_init1<<<dim3(32), dim3(256), 0, stream>>>(init, h0i1, c0i1, h1i1, c1i1);
  k_gather<<<dim3(B_*T_), dim3(128), 0, stream>>>(ids1, emb, ebuf);
  k_tcvt<<<dim3(64, 16), dim3(256), 0, stream>>>(U1_0, ut0_1, 2048, 512, 512, 0, 1);
  k_tcvt<<<dim3(64, 16), dim3(256), 0, stream>>>(W1_0, wtmp,  2048, 512, 512, 0, 0);
  k_tcvt<<<dim3(64, 16), dim3(256), 0, stream>>>(W1_1, wu1_1, 2048, 512, 1024, 0, 1);
  k_tcvt<<<dim3(64, 16), dim3(256), 0, stream>>>(U1_1, wu1_1, 2048, 512, 1024, 512, 1);
  k_bpack<<<dim3(8),  dim3(256), 0, stream>>>(b1_0, bpk10, 512, 2048);
  k_bpack<<<dim3(8),  dim3(256), 0, stream>>>(b1_1, bpk11, 512, 2048);
  k_mm<0><<<dim3(16, 8), dim3(256), 0, stream>>>(ebuf, wtmp, nullptr, xw, 1024, 2048, 512);
  k_rnn<512, 64, 64><<<dim3(64), dim3(256), 0, stream>>>(ut0_1, wu1_1, xw, bpk10, bpk11,
      h0i1, h1i1, c0i1, c1i1, h0s1, h1s1, c0f1, c1f1, bar1);
  // projection 1
  if(wide){
    k_tcvt<<<dim3(1000, 16), dim3(256), 0, stream>>>(Wp1, wpT, V_, 0, 512, 0, 0);
    k_mm<0><<<dim3(250, 8), dim3(256), 0, stream>>>(h1s1, wpT, bp1, out1, 1024, V_, 512);
  } else {
    k_mm<1><<<dim3(250, 8), dim3(256), 0, stream>>>(h1s1, Wp1, bp1, out1, 1024, V_, 512);
  }

  // ================= RNN2 =================
  k_init2<<<dim3(64, 2), dim3(256), 0, stream>>>(init, h0s1, h1s1, c0f1, c1f1,
                                                 h2i0, h2i1, c2i0, c2i1);
  k_gather<<<dim3(B_*T_), dim3(128), 0, stream>>>(ids2, emb, ebuf);
  k_tcvt<<<dim3(128, 32), dim3(256), 0, stream>>>(U2_0, ut0_2, 4096, 1024, 1024, 0, 1);
  k_tcvt<<<dim3(128, 16), dim3(256), 0, stream>>>(W2_0, wtmp,  4096, 1024, 512, 0, 0);
  k_tcvt<<<dim3(128, 32), dim3(256), 0, stream>>>(W2_1, wu1_2, 4096, 1024, 2048, 0, 1);
  k_tcvt<<<dim3(128, 32), dim3(256), 0, stream>>>(U2_1, wu1_2, 4096, 1024, 2048, 1024, 1);
  k_bpack<<<dim3(16), dim3(256), 0, stream>>>(b2_0, bpk20, 1024, 4096);
  k_bpack<<<dim3(16), dim3(256), 0, stream>>>(b2_1, bpk21, 1024, 4096);
  k_mm<0><<<dim3(32, 8), dim3(256), 0, stream>>>(ebuf, wtmp, nullptr, xw, 1024, 4096, 512);
  k_rnn<1024, 64, 32><<<dim3(192), dim3(256), 0, stream>>>(ut0_2, wu1_2, xw, bpk20, bpk21,
      h2i0, h2i1, c2i0, c2i1, h0s2, h1s2, c0f2, c1f2, bar2);
  // projection 2
  if(wide){
    k_tcvt<<<dim3(1000, 32), dim3(256), 0, stream>>>(Wp2, wpT, V_, 0, 1024, 0, 0);
    k_mm<0><<<dim3(250, 8), dim3(256), 0, stream>>>(h1s2, wpT, bp2, out2, 1024, V_, 1024);
  } else {
    k_mm<1><<<dim3(250, 8), dim3(256), 0, stream>>>(h1s2, Wp2, bp2, out2, 1024, V_, 1024);
  }
}